// Round 5
// baseline (2486.492 us; speedup 1.0000x reference)
//
#include <hip/hip_runtime.h>
#include <math.h>

#define NB 256
#define NS 100
#define ND 512
#define NH 8
#define NDFF 2048
#define NL 4
#define NM (NB * NS)  // 25600 tokens

typedef unsigned short u16;
typedef unsigned short u16x4 __attribute__((ext_vector_type(4)));
typedef unsigned short u16x8 __attribute__((ext_vector_type(8)));
typedef __bf16 bf16x8 __attribute__((ext_vector_type(8)));
typedef float f32x4 __attribute__((ext_vector_type(4)));

__device__ __forceinline__ float b2f(u16 u) {
  unsigned v = ((unsigned)u) << 16;
  return __builtin_bit_cast(float, v);
}
__device__ __forceinline__ u16 f2b(float f) {
  unsigned u = __builtin_bit_cast(unsigned, f);
  u += 0x7fffu + ((u >> 16) & 1u);
  return (u16)(u >> 16);
}
// async global->LDS, 16B per lane; LDS dest is wave-uniform base (HW adds lane*16)
__device__ __forceinline__ void gload_lds16(const void* g, void* l) {
  __builtin_amdgcn_global_load_lds(
      (const __attribute__((address_space(1))) unsigned int*)g,
      (__attribute__((address_space(3))) unsigned int*)l, 16, 0, 0);
}

// ---------------------------------------------------------------------------
// f32 -> bf16 cast (weights)
// ---------------------------------------------------------------------------
__global__ __launch_bounds__(256) void cast_kernel(const float* __restrict__ in,
                                                   u16* __restrict__ out) {
  int i = blockIdx.x * 256 + threadIdx.x;
  float4 v = ((const float4*)in)[i];
  u16x4 o = {f2b(v.x), f2b(v.y), f2b(v.z), f2b(v.w)};
  ((u16x4*)out)[i] = o;
}

// ---------------------------------------------------------------------------
// x = emb + PE ; writes f32 x and bf16 mirror xb
// ---------------------------------------------------------------------------
__global__ __launch_bounds__(256) void add_pe_kernel(const float* __restrict__ emb,
                                                     float* __restrict__ x,
                                                     u16* __restrict__ xb) {
  int idx = blockIdx.x * 256 + threadIdx.x;
  int d = idx & (ND - 1);
  int s = (idx >> 9) % NS;
  float ang = (float)s * (float)(d & ~1) * (-4.6051701859880914f / (float)ND);
  float pe = (d & 1) ? __cosf(ang) : __sinf(ang);
  float v = emb[idx] + pe;
  x[idx] = v;
  xb[idx] = f2b(v);
}

// ---------------------------------------------------------------------------
// BIG GEMM: C = A @ W^T + bias (+R) (opt ReLU). 256x256 tile, BK=64, 8 waves
// (2Mx4N), per-wave 128x64 out. LDS 128KB: A/B double-buffered [256][64] with
// per-row XOR block swizzle (stored blk = logical blk ^ (row&7)); staged via
// global_load_lds w/ pre-swizzled SOURCE (rule #21). RAW s_barrier (no vmcnt
// drain!) + 4 quadrant-phases per K-tile; next-tile stages issued phases 0-1,
// waited (vmcnt 0) only at end of phase 3 -> loads stay in flight across
// barriers (T3/T4). setprio around MFMA (T5).
// Race safety: stages into buf[nxt] only after the end-of-iter barrier that
// postdates all reads of it; per-wave vmcnt(0)+barrier before reads of staged
// data. C/D: col=lane&15, row=(lane>>4)*4+j  [verified rounds 2-4].
// ---------------------------------------------------------------------------
template <bool RELU, bool OUTBF16, bool RESID>
__global__ __launch_bounds__(512, 2) void gemm_big(const u16* __restrict__ A,
                                                   const u16* __restrict__ W,
                                                   const float* __restrict__ bias,
                                                   const float* __restrict__ R,
                                                   float* __restrict__ Cf,
                                                   u16* __restrict__ Cb,
                                                   int N, int K) {
  __shared__ u16 As[2][256 * 64];
  __shared__ u16 Bs[2][256 * 64];
  const int t = threadIdx.x;
  const int lane = t & 63;
  const int wave = t >> 6;   // 0..7
  const int wr = wave >> 2;  // 0..1  (M half)
  const int wc = wave & 3;   // 0..3  (N quarter)
  const int m0 = blockIdx.y * 256, n0 = blockIdx.x * 256;

  // staging geometry: lane l covers row +(l>>3), pre-swizzled 16B block
  const int lr = lane >> 3;
  const int lblk = (lane & 7) ^ lr;

  // fragment geometry
  const int li = lane & 15, lg = lane >> 4, x7 = li & 7;

  f32x4 acc[8][4];
#pragma unroll
  for (int mf = 0; mf < 8; ++mf)
#pragma unroll
    for (int nf = 0; nf < 4; ++nf) acc[mf][nf] = (f32x4){0.f, 0.f, 0.f, 0.f};

  const int KT = K >> 6;  // K-tiles of 64

  // prologue: stage K-tile 0 into buf 0 (A0,A1,B0,B1; 8 loads/wave)
#pragma unroll
  for (int p = 0; p < 2; ++p)
#pragma unroll
    for (int j = 0; j < 2; ++j) {
      const int rg = p * 128 + wave * 16 + j * 8;
      gload_lds16(A + (size_t)(m0 + rg + lr) * K + lblk * 8, &As[0][rg * 64]);
      gload_lds16(W + (size_t)(n0 + rg + lr) * K + lblk * 8, &Bs[0][rg * 64]);
    }
  asm volatile("s_waitcnt vmcnt(0)" ::: "memory");
  __builtin_amdgcn_s_barrier();

  for (int i = 0; i < KT; ++i) {
    const int k0n = (i + 1) << 6;
    const int cur = i & 1, nxt = cur ^ 1;
    const bool hasNext = (i + 1 < KT);
#pragma unroll
    for (int ph = 0; ph < 4; ++ph) {
      const int mq = ph >> 1, nq = ph & 1;  // quadrant of wave's 128x64
      bf16x8 af[4][2], bfr[2][2];
#pragma unroll
      for (int fi = 0; fi < 4; ++fi)
#pragma unroll
        for (int ks = 0; ks < 2; ++ks) {
          const int r = wr * 128 + (mq * 4 + fi) * 16 + li;
          af[fi][ks] = __builtin_bit_cast(
              bf16x8, *(const u16x8*)&As[cur][r * 64 + ((ks * 4 + lg) ^ x7) * 8]);
        }
#pragma unroll
      for (int gi = 0; gi < 2; ++gi)
#pragma unroll
        for (int ks = 0; ks < 2; ++ks) {
          const int r = wc * 64 + (nq * 2 + gi) * 16 + li;
          bfr[gi][ks] = __builtin_bit_cast(
              bf16x8, *(const u16x8*)&Bs[cur][r * 64 + ((ks * 4 + lg) ^ x7) * 8]);
        }
      if (ph < 2 && hasNext) {  // stage piece 'ph' (A and B) of next K-tile
#pragma unroll
        for (int j = 0; j < 2; ++j) {
          const int rg = ph * 128 + wave * 16 + j * 8;
          gload_lds16(A + (size_t)(m0 + rg + lr) * K + k0n + lblk * 8, &As[nxt][rg * 64]);
          gload_lds16(W + (size_t)(n0 + rg + lr) * K + k0n + lblk * 8, &Bs[nxt][rg * 64]);
        }
      }
      __builtin_amdgcn_s_barrier();
      __builtin_amdgcn_s_setprio(1);
#pragma unroll
      for (int ks = 0; ks < 2; ++ks)
#pragma unroll
        for (int fi = 0; fi < 4; ++fi)
#pragma unroll
          for (int gi = 0; gi < 2; ++gi)
            acc[mq * 4 + fi][nq * 2 + gi] = __builtin_amdgcn_mfma_f32_16x16x32_bf16(
                af[fi][ks], bfr[gi][ks], acc[mq * 4 + fi][nq * 2 + gi], 0, 0, 0);
      __builtin_amdgcn_s_setprio(0);
      if (ph == 3 && hasNext)  // next tile fully landed (per-wave) before barrier
        asm volatile("s_waitcnt vmcnt(0)" ::: "memory");
      __builtin_amdgcn_s_barrier();
    }
  }

#pragma unroll
  for (int mf = 0; mf < 8; ++mf) {
    const int row = m0 + wr * 128 + mf * 16 + lg * 4;
#pragma unroll
    for (int nf = 0; nf < 4; ++nf) {
      const int col = n0 + wc * 64 + nf * 16 + li;
      const float bv = bias[col];
#pragma unroll
      for (int j = 0; j < 4; ++j) {
        float v = acc[mf][nf][j] + bv;
        if (RESID) v += R[(size_t)(row + j) * N + col];
        if (RELU) v = fmaxf(v, 0.f);
        if (OUTBF16) Cb[(size_t)(row + j) * N + col] = f2b(v);
        else Cf[(size_t)(row + j) * N + col] = v;
      }
    }
  }
}

// ---------------------------------------------------------------------------
// Fallback 128x128 GEMM (round-4 proven) -- used only if workspace is tiny.
// ---------------------------------------------------------------------------
template <bool RELU, bool OUTBF16, bool RESID>
__global__ __launch_bounds__(256) void gemm_mfma(const u16* __restrict__ A,
                                                 const u16* __restrict__ W,
                                                 const float* __restrict__ bias,
                                                 const float* __restrict__ R,
                                                 float* __restrict__ Cf,
                                                 u16* __restrict__ Cb,
                                                 int N, int K) {
  __shared__ u16 As[128 * 64];
  __shared__ u16 Ws[128 * 64];
  const int t = threadIdx.x;
  const int lane = t & 63;
  const int wave = t >> 6;
  const int wr = wave >> 1, wc = wave & 1;
  const int m0 = blockIdx.y * 128, n0 = blockIdx.x * 128;
  const int srow = lane >> 3;
  const int sblk = (lane & 7) ^ srow;
  const u16* gA = A + (size_t)(m0 + wave * 8 + srow) * K + sblk * 8;
  const u16* gW = W + (size_t)(n0 + wave * 8 + srow) * K + sblk * 8;
  u16* lA = As + wave * 512;
  u16* lW = Ws + wave * 512;
  f32x4 acc[4][4];
#pragma unroll
  for (int m = 0; m < 4; ++m)
#pragma unroll
    for (int n = 0; n < 4; ++n) acc[m][n] = (f32x4){0.f, 0.f, 0.f, 0.f};
  const int lg = lane >> 4;
  const int li = lane & 15;
  const int l7 = li & 7;
  for (int k0 = 0; k0 < K; k0 += 64) {
    __syncthreads();
#pragma unroll
    for (int i = 0; i < 4; ++i) {
      gload_lds16(gA + k0 + (size_t)(32 * i) * K, lA + i * 2048);
      gload_lds16(gW + k0 + (size_t)(32 * i) * K, lW + i * 2048);
    }
    __syncthreads();
#pragma unroll
    for (int h = 0; h < 2; ++h) {
      bf16x8 af[4], bf_[4];
#pragma unroll
      for (int m = 0; m < 4; ++m) {
        int row = wr * 64 + m * 16 + li;
        af[m] = __builtin_bit_cast(
            bf16x8, *(const u16x8*)&As[row * 64 + (((h << 2) + lg) ^ l7) * 8]);
      }
#pragma unroll
      for (int n = 0; n < 4; ++n) {
        int row = wc * 64 + n * 16 + li;
        bf_[n] = __builtin_bit_cast(
            bf16x8, *(const u16x8*)&Ws[row * 64 + (((h << 2) + lg) ^ l7) * 8]);
      }
#pragma unroll
      for (int m = 0; m < 4; ++m)
#pragma unroll
        for (int n = 0; n < 4; ++n)
          acc[m][n] = __builtin_amdgcn_mfma_f32_16x16x32_bf16(af[m], bf_[n], acc[m][n], 0, 0, 0);
    }
  }
#pragma unroll
  for (int m = 0; m < 4; ++m) {
    int row = m0 + wr * 64 + m * 16 + lg * 4;
#pragma unroll
    for (int n = 0; n < 4; ++n) {
      int col = n0 + wc * 64 + n * 16 + li;
      float bv = bias[col];
#pragma unroll
      for (int j = 0; j < 4; ++j) {
        float v = acc[m][n][j] + bv;
        if (RESID) v += R[(size_t)(row + j) * N + col];
        if (RELU) v = fmaxf(v, 0.f);
        if (OUTBF16) Cb[(size_t)(row + j) * N + col] = f2b(v);
        else Cf[(size_t)(row + j) * N + col] = v;
      }
    }
  }
}

// ---------------------------------------------------------------------------
// Attention per (b,h), thread-per-query, ONLINE softmax fully in registers
// (T13 deferred rescale, thr=8). LDS 38.9 KB -> 4 blocks/CU. One barrier.
// ---------------------------------------------------------------------------
__global__ __launch_bounds__(128) void attn_kernel(const u16* __restrict__ qkv,
                                                   const int* __restrict__ mask,
                                                   u16* __restrict__ out) {
  const int bh = blockIdx.x;
  const int b = bh >> 3, h = bh & 7;
  __shared__ u16 Ksb[NS * 64];   // 12.8 KB
  __shared__ float Vs[NS * 64];  // 25.6 KB
  __shared__ float mb[NS + 4];
  const int t = threadIdx.x;
  const u16* base = qkv + (size_t)b * NS * 1536 + h * 64;

  for (int e = t; e < NS * 16; e += 128) {
    int s = e >> 4, d4 = (e & 15) << 2;
    *(u16x4*)&Ksb[s * 64 + d4] = *(const u16x4*)(base + (size_t)s * 1536 + 512 + d4);
    u16x4 vv = *(const u16x4*)(base + (size_t)s * 1536 + 1024 + d4);
    Vs[s * 64 + d4 + 0] = b2f(vv[0]);
    Vs[s * 64 + d4 + 1] = b2f(vv[1]);
    Vs[s * 64 + d4 + 2] = b2f(vv[2]);
    Vs[s * 64 + d4 + 3] = b2f(vv[3]);
  }
  if (t < NS) mb[t] = (mask[b * NS + t] == 0) ? -INFINITY : 0.f;

  float qf[64];
  if (t < NS) {
    const u16* gq = base + (size_t)t * 1536;
#pragma unroll
    for (int j = 0; j < 8; ++j) {
      u16x8 qq = *(const u16x8*)(gq + j * 8);
#pragma unroll
      for (int e = 0; e < 8; ++e) qf[j * 8 + e] = b2f(qq[e]) * 0.125f;
    }
  }
  __syncthreads();  // staging complete (the only barrier)
  if (t >= NS) return;

  f32x4 acc[16];
#pragma unroll
  for (int dq = 0; dq < 16; ++dq) acc[dq] = (f32x4){0.f, 0.f, 0.f, 0.f};
  float m = -INFINITY, sum = 0.f;

  for (int s = 0; s < NS; ++s) {
    float a0 = 0.f, a1 = 0.f, a2 = 0.f, a3 = 0.f;
#pragma unroll
    for (int j = 0; j < 8; ++j) {
      u16x8 kk = *(const u16x8*)&Ksb[s * 64 + j * 8];  // broadcast
      a0 += qf[j * 8 + 0] * b2f(kk[0]);
      a1 += qf[j * 8 + 1] * b2f(kk[1]);
      a2 += qf[j * 8 + 2] * b2f(kk[2]);
      a3 += qf[j * 8 + 3] * b2f(kk[3]);
      a0 += qf[j * 8 + 4] * b2f(kk[4]);
      a1 += qf[j * 8 + 5] * b2f(kk[5]);
      a2 += qf[j * 8 + 6] * b2f(kk[6]);
      a3 += qf[j * 8 + 7] * b2f(kk[7]);
    }
    float a = (a0 + a1) + (a2 + a3) + mb[s];
    if (a > m + 8.f) {
      float cs = __expf(m - a);
      sum *= cs;
#pragma unroll
      for (int dq = 0; dq < 16; ++dq) acc[dq] *= cs;
      m = a;
    }
    float p = __expf(a - m);
    sum += p;
#pragma unroll
    for (int dq = 0; dq < 16; ++dq)
      acc[dq] += p * *(const f32x4*)&Vs[s * 64 + dq * 4];  // broadcast
  }
  float inv = 1.f / sum;
  u16* op = out + ((size_t)b * NS + t) * ND + h * 64;
#pragma unroll
  for (int j = 0; j < 8; ++j) {
    u16x8 o;
#pragma unroll
    for (int e = 0; e < 8; ++e) {
      int d = j * 8 + e;
      o[e] = f2b(acc[d >> 2][d & 3] * inv);
    }
    *(u16x8*)(op + j * 8) = o;
  }
}

// ---------------------------------------------------------------------------
// x = LN(in) * g + b ; in already holds x + proj (residual fused in GEMM).
// ---------------------------------------------------------------------------
__global__ __launch_bounds__(128) void add_ln_kernel(const float* __restrict__ in,
                                                     float* __restrict__ x,
                                                     u16* __restrict__ xb,
                                                     const float* __restrict__ g,
                                                     const float* __restrict__ bb) {
  const int row = blockIdx.x;
  const int t = threadIdx.x;
  const size_t base = (size_t)row * ND + t * 4;
  float4 v = *(const float4*)(in + base);
  float s = (v.x + v.y) + (v.z + v.w);
  float q = (v.x * v.x + v.y * v.y) + (v.z * v.z + v.w * v.w);
#pragma unroll
  for (int off = 32; off; off >>= 1) {
    s += __shfl_down(s, off);
    q += __shfl_down(q, off);
  }
  __shared__ float sb[4];
  const int wid = t >> 6;
  if ((t & 63) == 0) { sb[wid * 2] = s; sb[wid * 2 + 1] = q; }
  __syncthreads();
  float ts = sb[0] + sb[2];
  float tq = sb[1] + sb[3];
  float mean = ts * (1.f / (float)ND);
  float var = tq * (1.f / (float)ND) - mean * mean;
  float rstd = rsqrtf(var + 1e-5f);
  float4 gg = *(const float4*)(g + t * 4);
  float4 bv = *(const float4*)(bb + t * 4);
  float o0 = (v.x - mean) * rstd * gg.x + bv.x;
  float o1 = (v.y - mean) * rstd * gg.y + bv.y;
  float o2 = (v.z - mean) * rstd * gg.z + bv.z;
  float o3 = (v.w - mean) * rstd * gg.w + bv.w;
  *(float4*)(x + base) = (float4){o0, o1, o2, o3};
  u16x4 ob = {f2b(o0), f2b(o1), f2b(o2), f2b(o3)};
  *(u16x4*)(xb + base) = ob;
}

// ---------------------------------------------------------------------------
// w2sum[d] = sum_o attn_w[o, D + d]   (s_q and attn_b cancel in the softmax)
// ---------------------------------------------------------------------------
__global__ __launch_bounds__(64) void w2sum_kernel(const float* __restrict__ attn_w,
                                                   float* __restrict__ w2sum) {
  int d = blockIdx.x * 64 + threadIdx.x;
  float s = 0.f;
  for (int o = 0; o < ND; ++o) s += attn_w[(size_t)o * 1024 + 512 + d];
  w2sum[d] = s;
}

// ---------------------------------------------------------------------------
// Pooling head: p = softmax_s(mask ? x[b,s].w2sum : -inf); out[b] = p @ x[b]
// ---------------------------------------------------------------------------
__global__ __launch_bounds__(256) void pool_kernel(const float* __restrict__ x,
                                                   const int* __restrict__ mask,
                                                   const float* __restrict__ w2sum,
                                                   float* __restrict__ out) {
  const int b = blockIdx.x;
  const int t = threadIdx.x;
  __shared__ float wsm[ND];
  __shared__ float sv[NS + 12];
  wsm[t] = w2sum[t];
  wsm[t + 256] = w2sum[t + 256];
  __syncthreads();
  const int wv = t >> 6, ln = t & 63;
  for (int s = wv; s < NS; s += 4) {
    const float* xr = x + ((size_t)b * NS + s) * ND;
    float acc = 0.f;
#pragma unroll
    for (int j = 0; j < 8; ++j) acc += xr[ln + j * 64] * wsm[ln + j * 64];
#pragma unroll
    for (int off = 32; off; off >>= 1) acc += __shfl_xor(acc, off);
    if (ln == 0) sv[s] = (mask[b * NS + s] != 0) ? acc : -INFINITY;
  }
  __syncthreads();
  float mx = -INFINITY;
  for (int s = 0; s < NS; ++s) mx = fmaxf(mx, sv[s]);
  if (t < NS) sv[t] = __expf(sv[t] - mx);
  __syncthreads();
  float sum = 0.f;
  for (int s = 0; s < NS; ++s) sum += sv[s];
  const float inv = 1.f / sum;
  float a0 = 0.f, a1 = 0.f;
  for (int s = 0; s < NS; ++s) {
    float p = sv[s];
    const float* xr = x + ((size_t)b * NS + s) * ND;
    a0 += p * xr[t];
    a1 += p * xr[t + 256];
  }
  out[(size_t)b * ND + t] = a0 * inv;
  out[(size_t)b * ND + t + 256] = a1 * inv;
}

// ---------------------------------------------------------------------------
extern "C" void kernel_launch(void* const* d_in, const int* in_sizes, int n_in,
                              void* d_out, int out_size, void* d_ws, size_t ws_size,
                              hipStream_t stream) {
  const int* mask = (const int*)d_in[0];
  const float* emb = (const float*)d_in[1];
  const float* in_proj_w = (const float*)d_in[2];
  const float* in_proj_b = (const float*)d_in[3];
  const float* out_proj_w = (const float*)d_in[4];
  const float* out_proj_b = (const float*)d_in[5];
  const float* lin1_w = (const float*)d_in[6];
  const float* lin1_b = (const float*)d_in[7];
  const float* lin2_w = (const float*)d_in[8];
  const float* lin2_b = (const float*)d_in[9];
  const float* ln1_w = (const float*)d_in[10];
  const float* ln1_b = (const float*)d_in[11];
  const float* ln2_w = (const float*)d_in[12];
  const float* ln2_b = (const float*)d_in[13];
  const float* attn_w = (const float*)d_in[14];
  // d_in[15] = attn_b: constant over softmax axis -> cancels; unused.

  char* wsb = (char*)d_ws;
  size_t off = 0;
  auto alloc = [&](size_t bytes) -> char* {
    char* p = wsb + off;
    off += (bytes + 255) & ~(size_t)255;
    return p;
  };
  float* x   = (float*)alloc((size_t)NM * ND * 4);
  u16* xb    = (u16*)alloc((size_t)NM * ND * 2);
  u16* wqkv  = (u16*)alloc((size_t)NL * 1536 * 512 * 2);
  u16* wout  = (u16*)alloc((size_t)NL * 512 * 512 * 2);
  u16* w1b   = (u16*)alloc((size_t)NL * 2048 * 512 * 2);
  u16* w2b   = (u16*)alloc((size_t)NL * 512 * 2048 * 2);
  float* w2s = (float*)alloc(ND * 4);
  size_t fixedEnd = off;

  // big path needs Mc % 256 == 0 -> BC in {256,128,64}; else 128^2 fallback
  int BC = 0;
  const int cands[3] = {256, 128, 64};
  auto alup = [](size_t b) { return (b + 255) & ~(size_t)255; };
  for (int ci = 0; ci < 3; ++ci) {
    size_t Mc = (size_t)cands[ci] * NS;
    size_t need = fixedEnd + alup(Mc * 2048 * 2) + alup(Mc * 512 * 2) + alup(Mc * 512 * 4);
    if (need <= ws_size) { BC = cands[ci]; break; }
  }
  const bool bigPath = (BC != 0);
  if (!bigPath) BC = 32;
  const size_t Mc = (size_t)BC * NS;
  u16* big    = (u16*)alloc(Mc * 2048 * 2);
  u16* bufA   = (u16*)alloc(Mc * 512 * 2);
  float* bufT = (float*)alloc(Mc * 512 * 4);

  cast_kernel<<<NL * 1536 * 512 / 1024, 256, 0, stream>>>(in_proj_w, wqkv);
  cast_kernel<<<NL * 512 * 512 / 1024, 256, 0, stream>>>(out_proj_w, wout);
  cast_kernel<<<NL * 2048 * 512 / 1024, 256, 0, stream>>>(lin1_w, w1b);
  cast_kernel<<<NL * 512 * 2048 / 1024, 256, 0, stream>>>(lin2_w, w2b);
  add_pe_kernel<<<NM * ND / 256, 256, 0, stream>>>(emb, x, xb);

  const int NC = NB / BC;
  for (int i = 0; i < NL; ++i) {
    for (int c = 0; c < NC; ++c) {
      float* xc = x + (size_t)c * Mc * ND;
      u16* xbc = xb + (size_t)c * Mc * ND;
      if (bigPath) {
        gemm_big<false, true, false><<<dim3(1536 / 256, Mc / 256), 512, 0, stream>>>(
            xbc, wqkv + (size_t)i * 1536 * 512, in_proj_b + i * 1536, nullptr, nullptr, big, 1536, 512);
        attn_kernel<<<BC * NH, 128, 0, stream>>>(big, mask + (size_t)c * BC * NS, bufA);
        gemm_big<false, false, true><<<dim3(512 / 256, Mc / 256), 512, 0, stream>>>(
            bufA, wout + (size_t)i * 512 * 512, out_proj_b + i * 512, xc, bufT, nullptr, 512, 512);
        add_ln_kernel<<<Mc, 128, 0, stream>>>(bufT, xc, xbc, ln1_w + i * 512, ln1_b + i * 512);
        gemm_big<true, true, false><<<dim3(2048 / 256, Mc / 256), 512, 0, stream>>>(
            xbc, w1b + (size_t)i * 2048 * 512, lin1_b + i * 2048, nullptr, nullptr, big, 2048, 512);
        gemm_big<false, false, true><<<dim3(512 / 256, Mc / 256), 512, 0, stream>>>(
            big, w2b + (size_t)i * 512 * 2048, lin2_b + i * 512, xc, bufT, nullptr, 512, 2048);
        add_ln_kernel<<<Mc, 128, 0, stream>>>(bufT, xc, xbc, ln2_w + i * 512, ln2_b + i * 512);
      } else {
        gemm_mfma<false, true, false><<<dim3(1536 / 128, Mc / 128), 256, 0, stream>>>(
            xbc, wqkv + (size_t)i * 1536 * 512, in_proj_b + i * 1536, nullptr, nullptr, big, 1536, 512);
        attn_kernel<<<BC * NH, 128, 0, stream>>>(big, mask + (size_t)c * BC * NS, bufA);
        gemm_mfma<false, false, true><<<dim3(512 / 128, Mc / 128), 256, 0, stream>>>(
            bufA, wout + (size_t)i * 512 * 512, out_proj_b + i * 512, xc, bufT, nullptr, 512, 512);
        add_ln_kernel<<<Mc, 128, 0, stream>>>(bufT, xc, xbc, ln1_w + i * 512, ln1_b + i * 512);
        gemm_mfma<true, true, false><<<dim3(2048 / 128, Mc / 128), 256, 0, stream>>>(
            xbc, w1b + (size_t)i * 2048 * 512, lin1_b + i * 2048, nullptr, nullptr, big, 2048, 512);
        gemm_mfma<false, false, true><<<dim3(512 / 128, Mc / 128), 256, 0, stream>>>(
            big, w2b + (size_t)i * 512 * 2048, lin2_b + i * 512, xc, bufT, nullptr, 512, 2048);
        add_ln_kernel<<<Mc, 128, 0, stream>>>(bufT, xc, xbc, ln2_w + i * 512, ln2_b + i * 512);
      }
    }
  }

  w2sum_kernel<<<ND / 64, 64, 0, stream>>>(attn_w, w2s);
  pool_kernel<<<NB, 256, 0, stream>>>(x, mask, w2s, (float*)d_out);
}

// Round 6
// 1970.177 us; speedup vs baseline: 1.2621x; 1.2621x over previous
//
#include <hip/hip_runtime.h>
#include <math.h>

#define NB 256
#define NS 100
#define ND 512
#define NH 8
#define NDFF 2048
#define NL 4
#define NM (NB * NS)  // 25600 tokens

typedef unsigned short u16;
typedef unsigned short u16x4 __attribute__((ext_vector_type(4)));
typedef unsigned short u16x8 __attribute__((ext_vector_type(8)));
typedef __bf16 bf16x8 __attribute__((ext_vector_type(8)));
typedef float f32x4 __attribute__((ext_vector_type(4)));
typedef _Float16 f16x2 __attribute__((ext_vector_type(2)));
typedef _Float16 f16x8 __attribute__((ext_vector_type(8)));

#if __has_builtin(__builtin_amdgcn_fdot2)
#define USE_FDOT2 1
#else
#define USE_FDOT2 0
#endif

__device__ __forceinline__ float b2f(u16 u) {
  unsigned v = ((unsigned)u) << 16;
  return __builtin_bit_cast(float, v);
}
__device__ __forceinline__ u16 f2b(float f) {
  unsigned u = __builtin_bit_cast(unsigned, f);
  u += 0x7fffu + ((u >> 16) & 1u);
  return (u16)(u >> 16);
}
// async global->LDS, 16B per lane; LDS dest is wave-uniform base (HW adds lane*16)
__device__ __forceinline__ void gload_lds16(const void* g, void* l) {
  __builtin_amdgcn_global_load_lds(
      (const __attribute__((address_space(1))) unsigned int*)g,
      (__attribute__((address_space(3))) unsigned int*)l, 16, 0, 0);
}

// ---------------------------------------------------------------------------
// f32 -> bf16 cast (weights)
// ---------------------------------------------------------------------------
__global__ __launch_bounds__(256) void cast_kernel(const float* __restrict__ in,
                                                   u16* __restrict__ out) {
  int i = blockIdx.x * 256 + threadIdx.x;
  float4 v = ((const float4*)in)[i];
  u16x4 o = {f2b(v.x), f2b(v.y), f2b(v.z), f2b(v.w)};
  ((u16x4*)out)[i] = o;
}

// ---------------------------------------------------------------------------
// x = emb + PE ; writes f32 x and bf16 mirror xb
// ---------------------------------------------------------------------------
__global__ __launch_bounds__(256) void add_pe_kernel(const float* __restrict__ emb,
                                                     float* __restrict__ x,
                                                     u16* __restrict__ xb) {
  int idx = blockIdx.x * 256 + threadIdx.x;
  int d = idx & (ND - 1);
  int s = (idx >> 9) % NS;
  float ang = (float)s * (float)(d & ~1) * (-4.6051701859880914f / (float)ND);
  float pe = (d & 1) ? __cosf(ang) : __sinf(ang);
  float v = emb[idx] + pe;
  x[idx] = v;
  xb[idx] = f2b(v);
}

// ---------------------------------------------------------------------------
// C = A @ W^T + bias (+R residual) (optional ReLU). A: MxK bf16, W: NxK bf16.
// ROUND-4 PROVEN: 128x128 tile, BK=64, 4 waves (2x2). Linear LDS [128][64] via
// global_load_lds w/ pre-swizzled global source (rule #21); ds_read applies
// blk ^= (row&7) -> conflict-free. ~4 blocks/CU implicit overlap (m114).
// C/D: col = lane&15, row = (lane>>4)*4 + j   [verified rounds 2-4]
// ---------------------------------------------------------------------------
template <bool RELU, bool OUTBF16, bool RESID>
__global__ __launch_bounds__(256) void gemm_mfma(const u16* __restrict__ A,
                                                 const u16* __restrict__ W,
                                                 const float* __restrict__ bias,
                                                 const float* __restrict__ R,
                                                 float* __restrict__ Cf,
                                                 u16* __restrict__ Cb,
                                                 int N, int K) {
  __shared__ u16 As[128 * 64];
  __shared__ u16 Ws[128 * 64];
  const int t = threadIdx.x;
  const int lane = t & 63;
  const int wave = t >> 6;
  const int wr = wave >> 1, wc = wave & 1;
  const int m0 = blockIdx.y * 128, n0 = blockIdx.x * 128;
  const int srow = lane >> 3;
  const int sblk = (lane & 7) ^ srow;
  const u16* gA = A + (size_t)(m0 + wave * 8 + srow) * K + sblk * 8;
  const u16* gW = W + (size_t)(n0 + wave * 8 + srow) * K + sblk * 8;
  u16* lA = As + wave * 512;
  u16* lW = Ws + wave * 512;
  f32x4 acc[4][4];
#pragma unroll
  for (int m = 0; m < 4; ++m)
#pragma unroll
    for (int n = 0; n < 4; ++n) acc[m][n] = (f32x4){0.f, 0.f, 0.f, 0.f};
  const int lg = lane >> 4;
  const int li = lane & 15;
  const int l7 = li & 7;
  for (int k0 = 0; k0 < K; k0 += 64) {
    __syncthreads();
#pragma unroll
    for (int i = 0; i < 4; ++i) {
      gload_lds16(gA + k0 + (size_t)(32 * i) * K, lA + i * 2048);
      gload_lds16(gW + k0 + (size_t)(32 * i) * K, lW + i * 2048);
    }
    __syncthreads();
#pragma unroll
    for (int h = 0; h < 2; ++h) {
      bf16x8 af[4], bf_[4];
#pragma unroll
      for (int m = 0; m < 4; ++m) {
        int row = wr * 64 + m * 16 + li;
        af[m] = __builtin_bit_cast(
            bf16x8, *(const u16x8*)&As[row * 64 + (((h << 2) + lg) ^ l7) * 8]);
      }
#pragma unroll
      for (int n = 0; n < 4; ++n) {
        int row = wc * 64 + n * 16 + li;
        bf_[n] = __builtin_bit_cast(
            bf16x8, *(const u16x8*)&Ws[row * 64 + (((h << 2) + lg) ^ l7) * 8]);
      }
#pragma unroll
      for (int m = 0; m < 4; ++m)
#pragma unroll
        for (int n = 0; n < 4; ++n)
          acc[m][n] = __builtin_amdgcn_mfma_f32_16x16x32_bf16(af[m], bf_[n], acc[m][n], 0, 0, 0);
    }
  }
#pragma unroll
  for (int m = 0; m < 4; ++m) {
    int row = m0 + wr * 64 + m * 16 + lg * 4;
#pragma unroll
    for (int n = 0; n < 4; ++n) {
      int col = n0 + wc * 64 + n * 16 + li;
      float bv = bias[col];
#pragma unroll
      for (int j = 0; j < 4; ++j) {
        float v = acc[m][n][j] + bv;
        if (RESID) v += R[(size_t)(row + j) * N + col];
        if (RELU) v = fmaxf(v, 0.f);
        if (OUTBF16) Cb[(size_t)(row + j) * N + col] = f2b(v);
        else Cf[(size_t)(row + j) * N + col] = v;
      }
    }
  }
}

// ---------------------------------------------------------------------------
// Attention per (b,h), thread-per-query, online softmax in registers (T13
// deferred rescale thr=8). LDS 38.9 KB -> 4 blocks/CU, one barrier.
// NEW: K stored as f16 in LDS; QK inner product via v_dot2_f32_f16
// (__builtin_amdgcn_fdot2) -> 4 insts per 8 elems instead of 16 (bf16->f16 is
// exact at these magnitudes; products accumulate in f32; 1/8 scale applied
// once per score). Falls back to bf16 shift+fma if builtin is unavailable.
// ---------------------------------------------------------------------------
__global__ __launch_bounds__(128) void attn_kernel(const u16* __restrict__ qkv,
                                                   const int* __restrict__ mask,
                                                   u16* __restrict__ out) {
  const int bh = blockIdx.x;
  const int b = bh >> 3, h = bh & 7;
  __shared__ u16 Ksb[NS * 64];   // 12.8 KB (f16 bits if USE_FDOT2, else bf16)
  __shared__ float Vs[NS * 64];  // 25.6 KB
  __shared__ float mb[NS + 4];
  const int t = threadIdx.x;
  const u16* base = qkv + (size_t)b * NS * 1536 + h * 64;

  for (int e = t; e < NS * 16; e += 128) {
    int s = e >> 4, d4 = (e & 15) << 2;
    u16x4 kk = *(const u16x4*)(base + (size_t)s * 1536 + 512 + d4);
#if USE_FDOT2
    u16x4 kh;
#pragma unroll
    for (int q = 0; q < 4; ++q) {
      _Float16 hv = (_Float16)b2f(kk[q]);  // exact bf16->f16
      kh[q] = __builtin_bit_cast(u16, hv);
    }
    *(u16x4*)&Ksb[s * 64 + d4] = kh;
#else
    *(u16x4*)&Ksb[s * 64 + d4] = kk;
#endif
    u16x4 vv = *(const u16x4*)(base + (size_t)s * 1536 + 1024 + d4);
    Vs[s * 64 + d4 + 0] = b2f(vv[0]);
    Vs[s * 64 + d4 + 1] = b2f(vv[1]);
    Vs[s * 64 + d4 + 2] = b2f(vv[2]);
    Vs[s * 64 + d4 + 3] = b2f(vv[3]);
  }
  if (t < NS) mb[t] = (mask[b * NS + t] == 0) ? -INFINITY : 0.f;

#if USE_FDOT2
  f16x2 qh[32];
#else
  float qf[64];
#endif
  if (t < NS) {
    const u16* gq = base + (size_t)t * 1536;
#pragma unroll
    for (int j = 0; j < 8; ++j) {
      u16x8 qq = *(const u16x8*)(gq + j * 8);
#if USE_FDOT2
#pragma unroll
      for (int e = 0; e < 4; ++e) {
        f16x2 p;
        p[0] = (_Float16)b2f(qq[e * 2 + 0]);
        p[1] = (_Float16)b2f(qq[e * 2 + 1]);
        qh[j * 4 + e] = p;
      }
#else
#pragma unroll
      for (int e = 0; e < 8; ++e) qf[j * 8 + e] = b2f(qq[e]) * 0.125f;
#endif
    }
  }
  __syncthreads();  // staging complete (the only barrier)
  if (t >= NS) return;

  f32x4 acc[16];
#pragma unroll
  for (int dq = 0; dq < 16; ++dq) acc[dq] = (f32x4){0.f, 0.f, 0.f, 0.f};
  float m = -INFINITY, sum = 0.f;

  for (int s = 0; s < NS; ++s) {
    float a0 = 0.f, a1 = 0.f, a2 = 0.f, a3 = 0.f;
#if USE_FDOT2
#pragma unroll
    for (int j = 0; j < 8; ++j) {
      f16x8 kk = __builtin_bit_cast(f16x8, *(const u16x8*)&Ksb[s * 64 + j * 8]);
      f16x2 k0 = {kk[0], kk[1]}, k1 = {kk[2], kk[3]};
      f16x2 k2 = {kk[4], kk[5]}, k3 = {kk[6], kk[7]};
      a0 = __builtin_amdgcn_fdot2(qh[j * 4 + 0], k0, a0, false);
      a1 = __builtin_amdgcn_fdot2(qh[j * 4 + 1], k1, a1, false);
      a2 = __builtin_amdgcn_fdot2(qh[j * 4 + 2], k2, a2, false);
      a3 = __builtin_amdgcn_fdot2(qh[j * 4 + 3], k3, a3, false);
    }
    float a = ((a0 + a1) + (a2 + a3)) * 0.125f + mb[s];
#else
#pragma unroll
    for (int j = 0; j < 8; ++j) {
      u16x8 kk = *(const u16x8*)&Ksb[s * 64 + j * 8];  // broadcast
      a0 += qf[j * 8 + 0] * b2f(kk[0]);
      a1 += qf[j * 8 + 1] * b2f(kk[1]);
      a2 += qf[j * 8 + 2] * b2f(kk[2]);
      a3 += qf[j * 8 + 3] * b2f(kk[3]);
      a0 += qf[j * 8 + 4] * b2f(kk[4]);
      a1 += qf[j * 8 + 5] * b2f(kk[5]);
      a2 += qf[j * 8 + 6] * b2f(kk[6]);
      a3 += qf[j * 8 + 7] * b2f(kk[7]);
    }
    float a = (a0 + a1) + (a2 + a3) + mb[s];
#endif
    if (a > m + 8.f) {  // deferred rescale (rare; exec-masked)
      float cs = __expf(m - a);
      sum *= cs;
#pragma unroll
      for (int dq = 0; dq < 16; ++dq) acc[dq] *= cs;
      m = a;
    }
    float p = __expf(a - m);  // masked keys: exp(-inf - finite) = 0
    sum += p;
#pragma unroll
    for (int dq = 0; dq < 16; ++dq)
      acc[dq] += p * *(const f32x4*)&Vs[s * 64 + dq * 4];  // broadcast
  }
  float inv = 1.f / sum;
  u16* op = out + ((size_t)b * NS + t) * ND + h * 64;
#pragma unroll
  for (int j = 0; j < 8; ++j) {
    u16x8 o;
#pragma unroll
    for (int e = 0; e < 8; ++e) {
      int d = j * 8 + e;
      o[e] = f2b(acc[d >> 2][d & 3] * inv);
    }
    *(u16x8*)(op + j * 8) = o;
  }
}

// ---------------------------------------------------------------------------
// x = LN(in) * g + b ; in already holds x + proj (residual fused in GEMM).
// ---------------------------------------------------------------------------
__global__ __launch_bounds__(128) void add_ln_kernel(const float* __restrict__ in,
                                                     float* __restrict__ x,
                                                     u16* __restrict__ xb,
                                                     const float* __restrict__ g,
                                                     const float* __restrict__ bb) {
  const int row = blockIdx.x;
  const int t = threadIdx.x;
  const size_t base = (size_t)row * ND + t * 4;
  float4 v = *(const float4*)(in + base);
  float s = (v.x + v.y) + (v.z + v.w);
  float q = (v.x * v.x + v.y * v.y) + (v.z * v.z + v.w * v.w);
#pragma unroll
  for (int off = 32; off; off >>= 1) {
    s += __shfl_down(s, off);
    q += __shfl_down(q, off);
  }
  __shared__ float sb[4];
  const int wid = t >> 6;
  if ((t & 63) == 0) { sb[wid * 2] = s; sb[wid * 2 + 1] = q; }
  __syncthreads();
  float ts = sb[0] + sb[2];
  float tq = sb[1] + sb[3];
  float mean = ts * (1.f / (float)ND);
  float var = tq * (1.f / (float)ND) - mean * mean;
  float rstd = rsqrtf(var + 1e-5f);
  float4 gg = *(const float4*)(g + t * 4);
  float4 bv = *(const float4*)(bb + t * 4);
  float o0 = (v.x - mean) * rstd * gg.x + bv.x;
  float o1 = (v.y - mean) * rstd * gg.y + bv.y;
  float o2 = (v.z - mean) * rstd * gg.z + bv.z;
  float o3 = (v.w - mean) * rstd * gg.w + bv.w;
  *(float4*)(x + base) = (float4){o0, o1, o2, o3};
  u16x4 ob = {f2b(o0), f2b(o1), f2b(o2), f2b(o3)};
  *(u16x4*)(xb + base) = ob;
}

// ---------------------------------------------------------------------------
// w2sum[d] = sum_o attn_w[o, D + d]   (s_q and attn_b cancel in the softmax)
// ---------------------------------------------------------------------------
__global__ __launch_bounds__(64) void w2sum_kernel(const float* __restrict__ attn_w,
                                                   float* __restrict__ w2sum) {
  int d = blockIdx.x * 64 + threadIdx.x;
  float s = 0.f;
  for (int o = 0; o < ND; ++o) s += attn_w[(size_t)o * 1024 + 512 + d];
  w2sum[d] = s;
}

// ---------------------------------------------------------------------------
// Pooling head: p = softmax_s(mask ? x[b,s].w2sum : -inf); out[b] = p @ x[b]
// ---------------------------------------------------------------------------
__global__ __launch_bounds__(256) void pool_kernel(const float* __restrict__ x,
                                                   const int* __restrict__ mask,
                                                   const float* __restrict__ w2sum,
                                                   float* __restrict__ out) {
  const int b = blockIdx.x;
  const int t = threadIdx.x;
  __shared__ float wsm[ND];
  __shared__ float sv[NS + 12];
  wsm[t] = w2sum[t];
  wsm[t + 256] = w2sum[t + 256];
  __syncthreads();
  const int wv = t >> 6, ln = t & 63;
  for (int s = wv; s < NS; s += 4) {
    const float* xr = x + ((size_t)b * NS + s) * ND;
    float acc = 0.f;
#pragma unroll
    for (int j = 0; j < 8; ++j) acc += xr[ln + j * 64] * wsm[ln + j * 64];
#pragma unroll
    for (int off = 32; off; off >>= 1) acc += __shfl_xor(acc, off);
    if (ln == 0) sv[s] = (mask[b * NS + s] != 0) ? acc : -INFINITY;
  }
  __syncthreads();
  float mx = -INFINITY;
  for (int s = 0; s < NS; ++s) mx = fmaxf(mx, sv[s]);
  if (t < NS) sv[t] = __expf(sv[t] - mx);
  __syncthreads();
  float sum = 0.f;
  for (int s = 0; s < NS; ++s) sum += sv[s];
  const float inv = 1.f / sum;
  float a0 = 0.f, a1 = 0.f;
  for (int s = 0; s < NS; ++s) {
    float p = sv[s];
    const float* xr = x + ((size_t)b * NS + s) * ND;
    a0 += p * xr[t];
    a1 += p * xr[t + 256];
  }
  out[(size_t)b * ND + t] = a0 * inv;
  out[(size_t)b * ND + t + 256] = a1 * inv;
}

// ---------------------------------------------------------------------------
extern "C" void kernel_launch(void* const* d_in, const int* in_sizes, int n_in,
                              void* d_out, int out_size, void* d_ws, size_t ws_size,
                              hipStream_t stream) {
  const int* mask = (const int*)d_in[0];
  const float* emb = (const float*)d_in[1];
  const float* in_proj_w = (const float*)d_in[2];
  const float* in_proj_b = (const float*)d_in[3];
  const float* out_proj_w = (const float*)d_in[4];
  const float* out_proj_b = (const float*)d_in[5];
  const float* lin1_w = (const float*)d_in[6];
  const float* lin1_b = (const float*)d_in[7];
  const float* lin2_w = (const float*)d_in[8];
  const float* lin2_b = (const float*)d_in[9];
  const float* ln1_w = (const float*)d_in[10];
  const float* ln1_b = (const float*)d_in[11];
  const float* ln2_w = (const float*)d_in[12];
  const float* ln2_b = (const float*)d_in[13];
  const float* attn_w = (const float*)d_in[14];
  // d_in[15] = attn_b: constant over softmax axis -> cancels; unused.

  char* wsb = (char*)d_ws;
  size_t off = 0;
  auto alloc = [&](size_t bytes) -> char* {
    char* p = wsb + off;
    off += (bytes + 255) & ~(size_t)255;
    return p;
  };
  float* x   = (float*)alloc((size_t)NM * ND * 4);
  u16* xb    = (u16*)alloc((size_t)NM * ND * 2);
  u16* wqkv  = (u16*)alloc((size_t)NL * 1536 * 512 * 2);
  u16* wout  = (u16*)alloc((size_t)NL * 512 * 512 * 2);
  u16* w1b   = (u16*)alloc((size_t)NL * 2048 * 512 * 2);
  u16* w2b   = (u16*)alloc((size_t)NL * 512 * 2048 * 2);
  float* w2s = (float*)alloc(ND * 4);
  size_t fixedEnd = off;

  int BC = 32;
  const int cands[4] = {256, 128, 64, 32};
  auto alup = [](size_t b) { return (b + 255) & ~(size_t)255; };
  for (int ci = 0; ci < 4; ++ci) {
    size_t Mc = (size_t)cands[ci] * NS;
    size_t need = fixedEnd + alup(Mc * 2048 * 2) + alup(Mc * 512 * 2) + alup(Mc * 512 * 4);
    if (need <= ws_size) { BC = cands[ci]; break; }
  }
  const size_t Mc = (size_t)BC * NS;
  u16* big    = (u16*)alloc(Mc * 2048 * 2);
  u16* bufA   = (u16*)alloc(Mc * 512 * 2);
  float* bufT = (float*)alloc(Mc * 512 * 4);

  cast_kernel<<<NL * 1536 * 512 / 1024, 256, 0, stream>>>(in_proj_w, wqkv);
  cast_kernel<<<NL * 512 * 512 / 1024, 256, 0, stream>>>(out_proj_w, wout);
  cast_kernel<<<NL * 2048 * 512 / 1024, 256, 0, stream>>>(lin1_w, w1b);
  cast_kernel<<<NL * 512 * 2048 / 1024, 256, 0, stream>>>(lin2_w, w2b);
  add_pe_kernel<<<NM * ND / 256, 256, 0, stream>>>(emb, x, xb);

  const int NC = NB / BC;
  for (int i = 0; i < NL; ++i) {
    for (int c = 0; c < NC; ++c) {
      float* xc = x + (size_t)c * Mc * ND;
      u16* xbc = xb + (size_t)c * Mc * ND;
      gemm_mfma<false, true, false><<<dim3(1536 / 128, Mc / 128), 256, 0, stream>>>(
          xbc, wqkv + (size_t)i * 1536 * 512, in_proj_b + i * 1536, nullptr, nullptr, big, 1536, 512);
      attn_kernel<<<BC * NH, 128, 0, stream>>>(big, mask + (size_t)c * BC * NS, bufA);
      gemm_mfma<false, false, true><<<dim3(512 / 128, Mc / 128), 256, 0, stream>>>(
          bufA, wout + (size_t)i * 512 * 512, out_proj_b + i * 512, xc, bufT, nullptr, 512, 512);
      add_ln_kernel<<<Mc, 128, 0, stream>>>(bufT, xc, xbc, ln1_w + i * 512, ln1_b + i * 512);
      gemm_mfma<true, true, false><<<dim3(2048 / 128, Mc / 128), 256, 0, stream>>>(
          xbc, w1b + (size_t)i * 2048 * 512, lin1_b + i * 2048, nullptr, nullptr, big, 2048, 512);
      gemm_mfma<false, false, true><<<dim3(512 / 128, Mc / 128), 256, 0, stream>>>(
          big, w2b + (size_t)i * 512 * 2048, lin2_b + i * 512, xc, bufT, nullptr, 512, 2048);
      add_ln_kernel<<<Mc, 128, 0, stream>>>(bufT, xc, xbc, ln2_w + i * 512, ln2_b + i * 512);
    }
  }

  w2sum_kernel<<<ND / 64, 64, 0, stream>>>(attn_w, w2s);
  pool_kernel<<<NB, 256, 0, stream>>>(x, mask, w2s, (float*)d_out);
}

// Round 8
// 1478.762 us; speedup vs baseline: 1.6815x; 1.3323x over previous
//
#include <hip/hip_runtime.h>
#include <math.h>

#define NB 256
#define NS 100
#define ND 512
#define NH 8
#define NDFF 2048
#define NL 4
#define NM (NB * NS)  // 25600 tokens

typedef unsigned short u16;
typedef unsigned short u16x4 __attribute__((ext_vector_type(4)));
typedef unsigned short u16x8 __attribute__((ext_vector_type(8)));
typedef __bf16 bf16x8 __attribute__((ext_vector_type(8)));
typedef float f32x4 __attribute__((ext_vector_type(4)));
typedef _Float16 f16x2 __attribute__((ext_vector_type(2)));
typedef _Float16 f16x8 __attribute__((ext_vector_type(8)));

#if __has_builtin(__builtin_amdgcn_fdot2)
#define USE_FDOT2 1
#else
#define USE_FDOT2 0
#endif

__device__ __forceinline__ float b2f(u16 u) {
  unsigned v = ((unsigned)u) << 16;
  return __builtin_bit_cast(float, v);
}
__device__ __forceinline__ u16 f2b(float f) {
  unsigned u = __builtin_bit_cast(unsigned, f);
  u += 0x7fffu + ((u >> 16) & 1u);
  return (u16)(u >> 16);
}
// async global->LDS, 16B per lane; LDS dest is wave-uniform base (HW adds lane*16)
__device__ __forceinline__ void gload_lds16(const void* g, void* l) {
  __builtin_amdgcn_global_load_lds(
      (const __attribute__((address_space(1))) unsigned int*)g,
      (__attribute__((address_space(3))) unsigned int*)l, 16, 0, 0);
}

// ---------------------------------------------------------------------------
// f32 -> bf16 cast (weights)
// ---------------------------------------------------------------------------
__global__ __launch_bounds__(256) void cast_kernel(const float* __restrict__ in,
                                                   u16* __restrict__ out) {
  int i = blockIdx.x * 256 + threadIdx.x;
  float4 v = ((const float4*)in)[i];
  u16x4 o = {f2b(v.x), f2b(v.y), f2b(v.z), f2b(v.w)};
  ((u16x4*)out)[i] = o;
}

// ---------------------------------------------------------------------------
// Per-batch lengths (prefix mask) + exclusive scan + per-chunk token counts.
// ---------------------------------------------------------------------------
__global__ __launch_bounds__(256) void scan_kernel(const int* __restrict__ mask,
                                                   int* __restrict__ offs,
                                                   int* __restrict__ meta,
                                                   int BC, int NC) {
  const int b = threadIdx.x;
  const int* mp = mask + b * NS;
  int len = 0;
#pragma unroll
  for (int i = 0; i < NS; i += 4) {
    int4 v = *(const int4*)(mp + i);
    len += v.x + v.y + v.z + v.w;
  }
  int v = len;
#pragma unroll
  for (int off = 1; off < 64; off <<= 1) {
    int u = __shfl_up(v, off);
    if ((b & 63) >= off) v += u;
  }
  __shared__ int wsum[4];
  __shared__ int incl[256];
  if ((b & 63) == 63) wsum[b >> 6] = v;
  __syncthreads();
  int add = 0;
  for (int w = 0; w < (b >> 6); ++w) add += wsum[w];
  v += add;
  incl[b] = v;
  __syncthreads();
  offs[b + 1] = v;
  if (b == 0) offs[0] = 0;
  if (b < NC) meta[b] = incl[(b + 1) * BC - 1] - (b ? incl[b * BC - 1] : 0);
}

// ---------------------------------------------------------------------------
// Fused PE-add + COMPACTION gather: real token (b,s) -> compacted row of its
// chunk. One block per source token; padded tokens exit (prefix mask).
// ---------------------------------------------------------------------------
__global__ __launch_bounds__(128) void pe_compact_kernel(const float* __restrict__ emb,
                                                         const int* __restrict__ offs,
                                                         int BC,
                                                         float* __restrict__ x,
                                                         u16* __restrict__ xb) {
  const int tok = blockIdx.x;
  const int b = tok / NS, s = tok - b * NS;
  const int ob = offs[b];
  const int len = offs[b + 1] - ob;
  if (s >= len) return;
  const int c = b / BC;
  const size_t dst = ((size_t)c * BC * NS + (ob - offs[c * BC]) + s) * ND;
  const int t = threadIdx.x;
  const int d0 = t * 4;
  float4 ev = *(const float4*)(emb + (size_t)tok * ND + d0);
  float o[4];
#pragma unroll
  for (int e = 0; e < 4; ++e) {
    int d = d0 + e;
    float ang = (float)s * (float)(d & ~1) * (-4.6051701859880914f / (float)ND);
    float pe = (d & 1) ? __cosf(ang) : __sinf(ang);
    o[e] = ((const float*)&ev)[e] + pe;
  }
  *(float4*)(x + dst + d0) = (float4){o[0], o[1], o[2], o[3]};
  u16x4 ob16 = {f2b(o[0]), f2b(o[1]), f2b(o[2]), f2b(o[3])};
  *(u16x4*)(xb + dst + d0) = ob16;
}

// ---------------------------------------------------------------------------
// C = A @ W^T + bias (+R residual) (optional ReLU). A: MxK bf16, W: NxK bf16.
// 128x128 tile, BK=64, 4 waves. Linear LDS via global_load_lds w/ pre-swizzled
// source; ds_read applies blk ^= (row&7) -> conflict-free.
// VARLEN: M-blocks beyond round-up-128(*pMr) exit early (uniform, pre-barrier).
// ---------------------------------------------------------------------------
template <bool RELU, bool OUTBF16, bool RESID>
__global__ __launch_bounds__(256) void gemm_mfma(const u16* __restrict__ A,
                                                 const u16* __restrict__ W,
                                                 const float* __restrict__ bias,
                                                 const float* __restrict__ R,
                                                 float* __restrict__ Cf,
                                                 u16* __restrict__ Cb,
                                                 const int* __restrict__ pMr,
                                                 int N, int K) {
  const int m0 = blockIdx.y * 128, n0 = blockIdx.x * 128;
  if (m0 >= ((*pMr + 127) & ~127)) return;  // uniform early-exit (pad tiles)
  __shared__ u16 As[128 * 64];
  __shared__ u16 Ws[128 * 64];
  const int t = threadIdx.x;
  const int lane = t & 63;
  const int wave = t >> 6;
  const int wr = wave >> 1, wc = wave & 1;
  const int srow = lane >> 3;
  const int sblk = (lane & 7) ^ srow;
  const u16* gA = A + (size_t)(m0 + wave * 8 + srow) * K + sblk * 8;
  const u16* gW = W + (size_t)(n0 + wave * 8 + srow) * K + sblk * 8;
  u16* lA = As + wave * 512;
  u16* lW = Ws + wave * 512;
  f32x4 acc[4][4];
#pragma unroll
  for (int m = 0; m < 4; ++m)
#pragma unroll
    for (int n = 0; n < 4; ++n) acc[m][n] = (f32x4){0.f, 0.f, 0.f, 0.f};
  const int lg = lane >> 4;
  const int li = lane & 15;
  const int l7 = li & 7;
  for (int k0 = 0; k0 < K; k0 += 64) {
    __syncthreads();
#pragma unroll
    for (int i = 0; i < 4; ++i) {
      gload_lds16(gA + k0 + (size_t)(32 * i) * K, lA + i * 2048);
      gload_lds16(gW + k0 + (size_t)(32 * i) * K, lW + i * 2048);
    }
    __syncthreads();
#pragma unroll
    for (int h = 0; h < 2; ++h) {
      bf16x8 af[4], bf_[4];
#pragma unroll
      for (int m = 0; m < 4; ++m) {
        int row = wr * 64 + m * 16 + li;
        af[m] = __builtin_bit_cast(
            bf16x8, *(const u16x8*)&As[row * 64 + (((h << 2) + lg) ^ l7) * 8]);
      }
#pragma unroll
      for (int n = 0; n < 4; ++n) {
        int row = wc * 64 + n * 16 + li;
        bf_[n] = __builtin_bit_cast(
            bf16x8, *(const u16x8*)&Ws[row * 64 + (((h << 2) + lg) ^ l7) * 8]);
      }
#pragma unroll
      for (int m = 0; m < 4; ++m)
#pragma unroll
        for (int n = 0; n < 4; ++n)
          acc[m][n] = __builtin_amdgcn_mfma_f32_16x16x32_bf16(af[m], bf_[n], acc[m][n], 0, 0, 0);
    }
  }
#pragma unroll
  for (int m = 0; m < 4; ++m) {
    int row = m0 + wr * 64 + m * 16 + lg * 4;
#pragma unroll
    for (int n = 0; n < 4; ++n) {
      int col = n0 + wc * 64 + n * 16 + li;
      float bv = bias[col];
#pragma unroll
      for (int j = 0; j < 4; ++j) {
        float v = acc[m][n][j] + bv;
        if (RESID) v += R[(size_t)(row + j) * N + col];
        if (RELU) v = fmaxf(v, 0.f);
        if (OUTBF16) Cb[(size_t)(row + j) * N + col] = f2b(v);
        else Cf[(size_t)(row + j) * N + col] = v;
      }
    }
  }
}

// ---------------------------------------------------------------------------
// VARLEN attention per (b,h), thread-per-query, online softmax in registers.
// ---------------------------------------------------------------------------
__global__ __launch_bounds__(128) void attn_kernel(const u16* __restrict__ qkv,
                                                   const int* __restrict__ offs,
                                                   int bBase,
                                                   u16* __restrict__ out) {
  const int bh = blockIdx.x;
  const int bl = bh >> 3, h = bh & 7;
  const int bg = bBase + bl;
  const int ob = offs[bg] - offs[bBase];
  const int len = offs[bg + 1] - offs[bg];  // >= 1
  __shared__ u16 Ksb[NS * 64];   // f16 bits if USE_FDOT2, else bf16
  __shared__ float Vs[NS * 64];
  const int t = threadIdx.x;
  const u16* base = qkv + (size_t)ob * 1536 + h * 64;

  for (int e = t; e < len * 16; e += 128) {
    int s = e >> 4, d4 = (e & 15) << 2;
    u16x4 kk = *(const u16x4*)(base + (size_t)s * 1536 + 512 + d4);
#if USE_FDOT2
    u16x4 kh;
#pragma unroll
    for (int q = 0; q < 4; ++q) {
      _Float16 hv = (_Float16)b2f(kk[q]);  // exact bf16->f16
      kh[q] = __builtin_bit_cast(u16, hv);
    }
    *(u16x4*)&Ksb[s * 64 + d4] = kh;
#else
    *(u16x4*)&Ksb[s * 64 + d4] = kk;
#endif
    u16x4 vv = *(const u16x4*)(base + (size_t)s * 1536 + 1024 + d4);
    Vs[s * 64 + d4 + 0] = b2f(vv[0]);
    Vs[s * 64 + d4 + 1] = b2f(vv[1]);
    Vs[s * 64 + d4 + 2] = b2f(vv[2]);
    Vs[s * 64 + d4 + 3] = b2f(vv[3]);
  }

#if USE_FDOT2
  f16x2 qh[32];
#else
  float qf[64];
#endif
  if (t < len) {
    const u16* gq = base + (size_t)t * 1536;
#pragma unroll
    for (int j = 0; j < 8; ++j) {
      u16x8 qq = *(const u16x8*)(gq + j * 8);
#if USE_FDOT2
#pragma unroll
      for (int e = 0; e < 4; ++e) {
        f16x2 p;
        p[0] = (_Float16)b2f(qq[e * 2 + 0]);
        p[1] = (_Float16)b2f(qq[e * 2 + 1]);
        qh[j * 4 + e] = p;
      }
#else
#pragma unroll
      for (int e = 0; e < 8; ++e) qf[j * 8 + e] = b2f(qq[e]) * 0.125f;
#endif
    }
  }
  __syncthreads();  // staging complete (the only barrier)
  if (t >= len) return;

  f32x4 acc[16];
#pragma unroll
  for (int dq = 0; dq < 16; ++dq) acc[dq] = (f32x4){0.f, 0.f, 0.f, 0.f};
  float m = -INFINITY, sum = 0.f;

  for (int s = 0; s < len; ++s) {
    float a0 = 0.f, a1 = 0.f, a2 = 0.f, a3 = 0.f;
#if USE_FDOT2
#pragma unroll
    for (int j = 0; j < 8; ++j) {
      f16x8 kk = __builtin_bit_cast(f16x8, *(const u16x8*)&Ksb[s * 64 + j * 8]);
      f16x2 k0 = {kk[0], kk[1]}, k1 = {kk[2], kk[3]};
      f16x2 k2 = {kk[4], kk[5]}, k3 = {kk[6], kk[7]};
      a0 = __builtin_amdgcn_fdot2(qh[j * 4 + 0], k0, a0, false);
      a1 = __builtin_amdgcn_fdot2(qh[j * 4 + 1], k1, a1, false);
      a2 = __builtin_amdgcn_fdot2(qh[j * 4 + 2], k2, a2, false);
      a3 = __builtin_amdgcn_fdot2(qh[j * 4 + 3], k3, a3, false);
    }
    float a = ((a0 + a1) + (a2 + a3)) * 0.125f;
#else
#pragma unroll
    for (int j = 0; j < 8; ++j) {
      u16x8 kk = *(const u16x8*)&Ksb[s * 64 + j * 8];  // broadcast
      a0 += qf[j * 8 + 0] * b2f(kk[0]);
      a1 += qf[j * 8 + 1] * b2f(kk[1]);
      a2 += qf[j * 8 + 2] * b2f(kk[2]);
      a3 += qf[j * 8 + 3] * b2f(kk[3]);
      a0 += qf[j * 8 + 4] * b2f(kk[4]);
      a1 += qf[j * 8 + 5] * b2f(kk[5]);
      a2 += qf[j * 8 + 6] * b2f(kk[6]);
      a3 += qf[j * 8 + 7] * b2f(kk[7]);
    }
    float a = (a0 + a1) + (a2 + a3);
#endif
    if (a > m + 8.f) {  // deferred rescale (T13); first key: exp(-inf)=0
      float cs = __expf(m - a);
      sum *= cs;
#pragma unroll
      for (int dq = 0; dq < 16; ++dq) acc[dq] *= cs;
      m = a;
    }
    float p = __expf(a - m);
    sum += p;
#pragma unroll
    for (int dq = 0; dq < 16; ++dq)
      acc[dq] += p * *(const f32x4*)&Vs[s * 64 + dq * 4];  // broadcast
  }
  float inv = 1.f / sum;
  u16* op = out + (size_t)(ob + t) * ND + h * 64;
#pragma unroll
  for (int j = 0; j < 8; ++j) {
    u16x8 o;
#pragma unroll
    for (int e = 0; e < 8; ++e) {
      int d = j * 8 + e;
      o[e] = f2b(acc[d >> 2][d & 3] * inv);
    }
    *(u16x8*)(op + j * 8) = o;
  }
}

// ---------------------------------------------------------------------------
// x = LN(in) * g + b ; VARLEN: rows >= *pMr exit (uniform, pre-barrier).
// ---------------------------------------------------------------------------
__global__ __launch_bounds__(128) void add_ln_kernel(const float* __restrict__ in,
                                                     float* __restrict__ x,
                                                     u16* __restrict__ xb,
                                                     const float* __restrict__ g,
                                                     const float* __restrict__ bb,
                                                     const int* __restrict__ pMr) {
  const int row = blockIdx.x;
  if (row >= *pMr) return;
  const int t = threadIdx.x;
  const size_t base = (size_t)row * ND + t * 4;
  float4 v = *(const float4*)(in + base);
  float s = (v.x + v.y) + (v.z + v.w);
  float q = (v.x * v.x + v.y * v.y) + (v.z * v.z + v.w * v.w);
#pragma unroll
  for (int off = 32; off; off >>= 1) {
    s += __shfl_down(s, off);
    q += __shfl_down(q, off);
  }
  __shared__ float sb[4];
  const int wid = t >> 6;
  if ((t & 63) == 0) { sb[wid * 2] = s; sb[wid * 2 + 1] = q; }
  __syncthreads();
  float ts = sb[0] + sb[2];
  float tq = sb[1] + sb[3];
  float mean = ts * (1.f / (float)ND);
  float var = tq * (1.f / (float)ND) - mean * mean;
  float rstd = rsqrtf(var + 1e-5f);
  float4 gg = *(const float4*)(g + t * 4);
  float4 bv = *(const float4*)(bb + t * 4);
  float o0 = (v.x - mean) * rstd * gg.x + bv.x;
  float o1 = (v.y - mean) * rstd * gg.y + bv.y;
  float o2 = (v.z - mean) * rstd * gg.z + bv.z;
  float o3 = (v.w - mean) * rstd * gg.w + bv.w;
  *(float4*)(x + base) = (float4){o0, o1, o2, o3};
  u16x4 ob = {f2b(o0), f2b(o1), f2b(o2), f2b(o3)};
  *(u16x4*)(xb + base) = ob;
}

// ---------------------------------------------------------------------------
// w2sum[d] = sum_o attn_w[o, D + d]   (s_q and attn_b cancel in the softmax)
// ---------------------------------------------------------------------------
__global__ __launch_bounds__(64) void w2sum_kernel(const float* __restrict__ attn_w,
                                                   float* __restrict__ w2sum) {
  int d = blockIdx.x * 64 + threadIdx.x;
  float s = 0.f;
  for (int o = 0; o < ND; ++o) s += attn_w[(size_t)o * 1024 + 512 + d];
  w2sum[d] = s;
}

// ---------------------------------------------------------------------------
// VARLEN pooling head, RACE-FREE rewrite: sv (raw scores) is write-once;
// max & sum via shfl_xor wave reductions + red[] with barriers; exp'd
// weights in a SEPARATE pv[] (no shared-mem RMW anywhere).
// [round-7 post-mortem: old serial-read mx loop raced with sv overwrite]
// ---------------------------------------------------------------------------
__global__ __launch_bounds__(256) void pool_kernel(const float* __restrict__ x,
                                                   const int* __restrict__ offs,
                                                   int BC,
                                                   const float* __restrict__ w2sum,
                                                   float* __restrict__ out) {
  const int b = blockIdx.x;
  const int c = b / BC;
  const int ob = offs[b] - offs[c * BC];
  const int len = offs[b + 1] - offs[b];  // >= 1
  const float* xr0 = x + ((size_t)c * BC * NS + ob) * ND;
  const int t = threadIdx.x;
  __shared__ float wsm[ND];
  __shared__ float sv[NS + 12];
  __shared__ float pv[256];
  __shared__ float red[8];
  wsm[t] = w2sum[t];
  wsm[t + 256] = w2sum[t + 256];
  __syncthreads();
  const int wv = t >> 6, ln = t & 63;
  // Phase A: raw scores -> sv (write-once, never modified after)
  for (int s = wv; s < len; s += 4) {
    const float* xr = xr0 + (size_t)s * ND;
    float acc = 0.f;
#pragma unroll
    for (int j = 0; j < 8; ++j) acc += xr[ln + j * 64] * wsm[ln + j * 64];
#pragma unroll
    for (int off = 32; off; off >>= 1) acc += __shfl_xor(acc, off);
    if (ln == 0) sv[s] = acc;
  }
  __syncthreads();
  // Phase B: max via wave reduction (reads sv only)
  float v = (t < len) ? sv[t] : -INFINITY;
  float m_ = v;
#pragma unroll
  for (int off = 32; off; off >>= 1) m_ = fmaxf(m_, __shfl_xor(m_, off));
  if (ln == 0) red[wv] = m_;
  __syncthreads();
  const float mx = fmaxf(fmaxf(red[0], red[1]), fmaxf(red[2], red[3]));
  // Phase C: exp into separate pv + sum via wave reduction
  float e = (t < len) ? __expf(v - mx) : 0.f;
  pv[t] = e;
  float s_ = e;
#pragma unroll
  for (int off = 32; off; off >>= 1) s_ += __shfl_xor(s_, off);
  if (ln == 0) red[4 + wv] = s_;
  __syncthreads();
  const float inv = 1.f / ((red[4] + red[5]) + (red[6] + red[7]));
  // Phase D: weighted sum (reads pv, written before the barrier above)
  float a0 = 0.f, a1 = 0.f;
  for (int s = 0; s < len; ++s) {
    float p = pv[s];
    const float* xr = xr0 + (size_t)s * ND;
    a0 += p * xr[t];
    a1 += p * xr[t + 256];
  }
  out[(size_t)b * ND + t] = a0 * inv;
  out[(size_t)b * ND + t + 256] = a1 * inv;
}

// ---------------------------------------------------------------------------
extern "C" void kernel_launch(void* const* d_in, const int* in_sizes, int n_in,
                              void* d_out, int out_size, void* d_ws, size_t ws_size,
                              hipStream_t stream) {
  const int* mask = (const int*)d_in[0];
  const float* emb = (const float*)d_in[1];
  const float* in_proj_w = (const float*)d_in[2];
  const float* in_proj_b = (const float*)d_in[3];
  const float* out_proj_w = (const float*)d_in[4];
  const float* out_proj_b = (const float*)d_in[5];
  const float* lin1_w = (const float*)d_in[6];
  const float* lin1_b = (const float*)d_in[7];
  const float* lin2_w = (const float*)d_in[8];
  const float* lin2_b = (const float*)d_in[9];
  const float* ln1_w = (const float*)d_in[10];
  const float* ln1_b = (const float*)d_in[11];
  const float* ln2_w = (const float*)d_in[12];
  const float* ln2_b = (const float*)d_in[13];
  const float* attn_w = (const float*)d_in[14];
  // d_in[15] = attn_b: constant over softmax axis -> cancels; unused.

  char* wsb = (char*)d_ws;
  size_t off = 0;
  auto alloc = [&](size_t bytes) -> char* {
    char* p = wsb + off;
    off += (bytes + 255) & ~(size_t)255;
    return p;
  };
  float* x   = (float*)alloc((size_t)NM * ND * 4);   // compacted, chunk-strided
  u16* xb    = (u16*)alloc((size_t)NM * ND * 2);     // compacted bf16 mirror
  u16* wqkv  = (u16*)alloc((size_t)NL * 1536 * 512 * 2);
  u16* wout  = (u16*)alloc((size_t)NL * 512 * 512 * 2);
  u16* w1b   = (u16*)alloc((size_t)NL * 2048 * 512 * 2);
  u16* w2b   = (u16*)alloc((size_t)NL * 512 * 2048 * 2);
  float* w2s = (float*)alloc(ND * 4);
  int* offs  = (int*)alloc((NB + 1) * 4);
  int* meta  = (int*)alloc(16 * 4);   // Mr per chunk (<= 8 chunks)
  size_t fixedEnd = off;

  int BC = 32;
  const int cands[4] = {256, 128, 64, 32};
  auto alup = [](size_t b) { return (b + 255) & ~(size_t)255; };
  for (int ci = 0; ci < 4; ++ci) {
    size_t Mc = (size_t)cands[ci] * NS;
    size_t need = fixedEnd + alup(Mc * 2048 * 2) + alup(Mc * 512 * 2) + alup(Mc * 512 * 4);
    if (need <= ws_size) { BC = cands[ci]; break; }
  }
  const size_t Mc = (size_t)BC * NS;
  const int NC = NB / BC;
  u16* big    = (u16*)alloc(Mc * 2048 * 2);
  u16* bufA   = (u16*)alloc(Mc * 512 * 2);
  float* bufT = (float*)alloc(Mc * 512 * 4);

  cast_kernel<<<NL * 1536 * 512 / 1024, 256, 0, stream>>>(in_proj_w, wqkv);
  cast_kernel<<<NL * 512 * 512 / 1024, 256, 0, stream>>>(out_proj_w, wout);
  cast_kernel<<<NL * 2048 * 512 / 1024, 256, 0, stream>>>(lin1_w, w1b);
  cast_kernel<<<NL * 512 * 2048 / 1024, 256, 0, stream>>>(lin2_w, w2b);
  scan_kernel<<<1, 256, 0, stream>>>(mask, offs, meta, BC, NC);
  pe_compact_kernel<<<NM, 128, 0, stream>>>(emb, offs, BC, x, xb);

  for (int i = 0; i < NL; ++i) {
    for (int c = 0; c < NC; ++c) {
      float* xc = x + (size_t)c * Mc * ND;
      u16* xbc = xb + (size_t)c * Mc * ND;
      const int* pMr = meta + c;
      gemm_mfma<false, true, false><<<dim3(1536 / 128, Mc / 128), 256, 0, stream>>>(
          xbc, wqkv + (size_t)i * 1536 * 512, in_proj_b + i * 1536, nullptr, nullptr, big, pMr, 1536, 512);
      attn_kernel<<<BC * NH, 128, 0, stream>>>(big, offs, c * BC, bufA);
      gemm_mfma<false, false, true><<<dim3(512 / 128, Mc / 128), 256, 0, stream>>>(
          bufA, wout + (size_t)i * 512 * 512, out_proj_b + i * 512, xc, bufT, nullptr, pMr, 512, 512);
      add_ln_kernel<<<Mc, 128, 0, stream>>>(bufT, xc, xbc, ln1_w + i * 512, ln1_b + i * 512, pMr);
      gemm_mfma<true, true, false><<<dim3(2048 / 128, Mc / 128), 256, 0, stream>>>(
          xbc, w1b + (size_t)i * 2048 * 512, lin1_b + i * 2048, nullptr, nullptr, big, pMr, 2048, 512);
      gemm_mfma<false, false, true><<<dim3(512 / 128, Mc / 128), 256, 0, stream>>>(
          big, w2b + (size_t)i * 512 * 2048, lin2_b + i * 512, xc, bufT, nullptr, pMr, 512, 2048);
      add_ln_kernel<<<Mc, 128, 0, stream>>>(bufT, xc, xbc, ln2_w + i * 512, ln2_b + i * 512, pMr);
    }
  }

  w2sum_kernel<<<ND / 64, 64, 0, stream>>>(attn_w, w2s);
  pool_kernel<<<NB, 256, 0, stream>>>(x, offs, BC, w2s, (float*)d_out);
}

// Round 9
// 1374.803 us; speedup vs baseline: 1.8086x; 1.0756x over previous
//
#include <hip/hip_runtime.h>
#include <math.h>

#define NB 256
#define NS 100
#define ND 512
#define NH 8
#define NDFF 2048
#define NL 4
#define NM (NB * NS)  // 25600 tokens

typedef unsigned short u16;
typedef unsigned short u16x4 __attribute__((ext_vector_type(4)));
typedef unsigned short u16x8 __attribute__((ext_vector_type(8)));
typedef __bf16 bf16x8 __attribute__((ext_vector_type(8)));
typedef float f32x4 __attribute__((ext_vector_type(4)));
typedef _Float16 f16x2 __attribute__((ext_vector_type(2)));
typedef _Float16 f16x8 __attribute__((ext_vector_type(8)));

#if __has_builtin(__builtin_amdgcn_fdot2)
#define USE_FDOT2 1
#else
#define USE_FDOT2 0
#endif

__device__ __forceinline__ float b2f(u16 u) {
  unsigned v = ((unsigned)u) << 16;
  return __builtin_bit_cast(float, v);
}
__device__ __forceinline__ u16 f2b(float f) {
  unsigned u = __builtin_bit_cast(unsigned, f);
  u += 0x7fffu + ((u >> 16) & 1u);
  return (u16)(u >> 16);
}
// async global->LDS, 16B per lane; LDS dest is wave-uniform base (HW adds lane*16)
__device__ __forceinline__ void gload_lds16(const void* g, void* l) {
  __builtin_amdgcn_global_load_lds(
      (const __attribute__((address_space(1))) unsigned int*)g,
      (__attribute__((address_space(3))) unsigned int*)l, 16, 0, 0);
}

// ---------------------------------------------------------------------------
// f32 -> bf16 cast (weights)
// ---------------------------------------------------------------------------
__global__ __launch_bounds__(256) void cast_kernel(const float* __restrict__ in,
                                                   u16* __restrict__ out) {
  int i = blockIdx.x * 256 + threadIdx.x;
  float4 v = ((const float4*)in)[i];
  u16x4 o = {f2b(v.x), f2b(v.y), f2b(v.z), f2b(v.w)};
  ((u16x4*)out)[i] = o;
}

// ---------------------------------------------------------------------------
// Per-batch lengths (prefix mask) + exclusive scan + per-chunk token counts.
// ---------------------------------------------------------------------------
__global__ __launch_bounds__(256) void scan_kernel(const int* __restrict__ mask,
                                                   int* __restrict__ offs,
                                                   int* __restrict__ meta,
                                                   int BC, int NC) {
  const int b = threadIdx.x;
  const int* mp = mask + b * NS;
  int len = 0;
#pragma unroll
  for (int i = 0; i < NS; i += 4) {
    int4 v = *(const int4*)(mp + i);
    len += v.x + v.y + v.z + v.w;
  }
  int v = len;
#pragma unroll
  for (int off = 1; off < 64; off <<= 1) {
    int u = __shfl_up(v, off);
    if ((b & 63) >= off) v += u;
  }
  __shared__ int wsum[4];
  __shared__ int incl[256];
  if ((b & 63) == 63) wsum[b >> 6] = v;
  __syncthreads();
  int add = 0;
  for (int w = 0; w < (b >> 6); ++w) add += wsum[w];
  v += add;
  incl[b] = v;
  __syncthreads();
  offs[b + 1] = v;
  if (b == 0) offs[0] = 0;
  if (b < NC) meta[b] = incl[(b + 1) * BC - 1] - (b ? incl[b * BC - 1] : 0);
}

// ---------------------------------------------------------------------------
// Fused PE-add + COMPACTION gather: real token (b,s) -> compacted row of its
// chunk. One block per source token; padded tokens exit (prefix mask).
// ---------------------------------------------------------------------------
__global__ __launch_bounds__(128) void pe_compact_kernel(const float* __restrict__ emb,
                                                         const int* __restrict__ offs,
                                                         int BC,
                                                         float* __restrict__ x,
                                                         u16* __restrict__ xb) {
  const int tok = blockIdx.x;
  const int b = tok / NS, s = tok - b * NS;
  const int ob = offs[b];
  const int len = offs[b + 1] - ob;
  if (s >= len) return;
  const int c = b / BC;
  const size_t dst = ((size_t)c * BC * NS + (ob - offs[c * BC]) + s) * ND;
  const int t = threadIdx.x;
  const int d0 = t * 4;
  float4 ev = *(const float4*)(emb + (size_t)tok * ND + d0);
  float o[4];
#pragma unroll
  for (int e = 0; e < 4; ++e) {
    int d = d0 + e;
    float ang = (float)s * (float)(d & ~1) * (-4.6051701859880914f / (float)ND);
    float pe = (d & 1) ? __cosf(ang) : __sinf(ang);
    o[e] = ((const float*)&ev)[e] + pe;
  }
  *(float4*)(x + dst + d0) = (float4){o[0], o[1], o[2], o[3]};
  u16x4 ob16 = {f2b(o[0]), f2b(o[1]), f2b(o[2]), f2b(o[3])};
  *(u16x4*)(xb + dst + d0) = ob16;
}

// ---------------------------------------------------------------------------
// C = A @ W^T + bias (+R residual) (optional ReLU). A: MxK bf16, W: NxK bf16.
// TM x 128 tile (TM=128 or 64), BK=64, 4 waves (2x2; wave rows = TM/2).
// Linear LDS via global_load_lds w/ pre-swizzled source; ds_read applies
// blk ^= (row&7) -> conflict-free. TM=64 doubles grid for small-N GEMMs
// (out_proj/ff2 had <1 block/CU at TM=128 -> 1 wave/SIMD, no latency hiding).
// VARLEN: M-blocks beyond round-up-TM(*pMr) exit early (uniform, pre-barrier).
// C/D: col = lane&15, row = (lane>>4)*4 + j   [verified rounds 2-8]
// ---------------------------------------------------------------------------
template <int TM, bool RELU, bool OUTBF16, bool RESID>
__global__ __launch_bounds__(256) void gemm_mfma(const u16* __restrict__ A,
                                                 const u16* __restrict__ W,
                                                 const float* __restrict__ bias,
                                                 const float* __restrict__ R,
                                                 float* __restrict__ Cf,
                                                 u16* __restrict__ Cb,
                                                 const int* __restrict__ pMr,
                                                 int N, int K) {
  constexpr int MF = TM / 32;  // m-fragments per wave (wave rows = 16*MF)
  const int m0 = blockIdx.y * TM, n0 = blockIdx.x * 128;
  if (m0 >= ((*pMr + TM - 1) & ~(TM - 1))) return;  // uniform early-exit
  __shared__ u16 As[TM * 64];
  __shared__ u16 Ws[128 * 64];
  const int t = threadIdx.x;
  const int lane = t & 63;
  const int wave = t >> 6;
  const int wr = wave >> 1, wc = wave & 1;
  const int srow = lane >> 3;
  const int sblk = (lane & 7) ^ srow;
  const u16* gA = A + (size_t)(m0 + wave * 8 + srow) * K + sblk * 8;
  const u16* gW = W + (size_t)(n0 + wave * 8 + srow) * K + sblk * 8;
  u16* lA = As + wave * 512;
  u16* lW = Ws + wave * 512;
  f32x4 acc[MF][4];
#pragma unroll
  for (int m = 0; m < MF; ++m)
#pragma unroll
    for (int n = 0; n < 4; ++n) acc[m][n] = (f32x4){0.f, 0.f, 0.f, 0.f};
  const int lg = lane >> 4;
  const int li = lane & 15;
  const int l7 = li & 7;
  for (int k0 = 0; k0 < K; k0 += 64) {
    __syncthreads();
#pragma unroll
    for (int i = 0; i < MF; ++i)
      gload_lds16(gA + k0 + (size_t)(32 * i) * K, lA + i * 2048);
#pragma unroll
    for (int i = 0; i < 4; ++i)
      gload_lds16(gW + k0 + (size_t)(32 * i) * K, lW + i * 2048);
    __syncthreads();
#pragma unroll
    for (int h = 0; h < 2; ++h) {
      bf16x8 af[MF], bf_[4];
#pragma unroll
      for (int m = 0; m < MF; ++m) {
        int row = wr * (16 * MF) + m * 16 + li;
        af[m] = __builtin_bit_cast(
            bf16x8, *(const u16x8*)&As[row * 64 + (((h << 2) + lg) ^ l7) * 8]);
      }
#pragma unroll
      for (int n = 0; n < 4; ++n) {
        int row = wc * 64 + n * 16 + li;
        bf_[n] = __builtin_bit_cast(
            bf16x8, *(const u16x8*)&Ws[row * 64 + (((h << 2) + lg) ^ l7) * 8]);
      }
#pragma unroll
      for (int m = 0; m < MF; ++m)
#pragma unroll
        for (int n = 0; n < 4; ++n)
          acc[m][n] = __builtin_amdgcn_mfma_f32_16x16x32_bf16(af[m], bf_[n], acc[m][n], 0, 0, 0);
    }
  }
#pragma unroll
  for (int m = 0; m < MF; ++m) {
    int row = m0 + wr * (16 * MF) + m * 16 + lg * 4;
#pragma unroll
    for (int n = 0; n < 4; ++n) {
      int col = n0 + wc * 64 + n * 16 + li;
      float bv = bias[col];
#pragma unroll
      for (int j = 0; j < 4; ++j) {
        float v = acc[m][n][j] + bv;
        if (RESID) v += R[(size_t)(row + j) * N + col];
        if (RELU) v = fmaxf(v, 0.f);
        if (OUTBF16) Cb[(size_t)(row + j) * N + col] = f2b(v);
        else Cf[(size_t)(row + j) * N + col] = v;
      }
    }
  }
}

// ---------------------------------------------------------------------------
// VARLEN attention per (b,h), 256 threads: lane pair (2q, 2q+1) splits query
// q's keys (ks = t&1 takes keys s = ks, ks+2, ...), each with independent
// online-softmax state; merged via CONVERGENT shfl_xor(.,1) (pairs are
// adjacent lanes in one wave; both active iff q < len). Ternary-selected
// constant register indices (rule #20: no runtime acc indexing). Each thread
// writes its 32-element output half. len==1: ks=1 partner has m=-inf ->
// cs2 = exp(-inf - finite) = 0, no NaN.
// ---------------------------------------------------------------------------
__global__ __launch_bounds__(256) void attn_kernel(const u16* __restrict__ qkv,
                                                   const int* __restrict__ offs,
                                                   int bBase,
                                                   u16* __restrict__ out) {
  const int bh = blockIdx.x;
  const int bl = bh >> 3, h = bh & 7;
  const int bg = bBase + bl;
  const int ob = offs[bg] - offs[bBase];
  const int len = offs[bg + 1] - offs[bg];  // >= 1
  __shared__ u16 Ksb[NS * 64];   // f16 bits if USE_FDOT2, else bf16
  __shared__ float Vs[NS * 64];
  const int t = threadIdx.x;
  const u16* base = qkv + (size_t)ob * 1536 + h * 64;

  for (int e = t; e < len * 16; e += 256) {
    int s = e >> 4, d4 = (e & 15) << 2;
    u16x4 kk = *(const u16x4*)(base + (size_t)s * 1536 + 512 + d4);
#if USE_FDOT2
    u16x4 kh;
#pragma unroll
    for (int q = 0; q < 4; ++q) {
      _Float16 hv = (_Float16)b2f(kk[q]);  // exact bf16->f16
      kh[q] = __builtin_bit_cast(u16, hv);
    }
    *(u16x4*)&Ksb[s * 64 + d4] = kh;
#else
    *(u16x4*)&Ksb[s * 64 + d4] = kk;
#endif
    u16x4 vv = *(const u16x4*)(base + (size_t)s * 1536 + 1024 + d4);
    Vs[s * 64 + d4 + 0] = b2f(vv[0]);
    Vs[s * 64 + d4 + 1] = b2f(vv[1]);
    Vs[s * 64 + d4 + 2] = b2f(vv[2]);
    Vs[s * 64 + d4 + 3] = b2f(vv[3]);
  }

  const int q = t >> 1, ks = t & 1;
#if USE_FDOT2
  f16x2 qh[32];
#else
  float qf[64];
#endif
  if (q < len) {
    const u16* gq = base + (size_t)q * 1536;
#pragma unroll
    for (int j = 0; j < 8; ++j) {
      u16x8 qq = *(const u16x8*)(gq + j * 8);
#if USE_FDOT2
#pragma unroll
      for (int e = 0; e < 4; ++e) {
        f16x2 p;
        p[0] = (_Float16)b2f(qq[e * 2 + 0]);
        p[1] = (_Float16)b2f(qq[e * 2 + 1]);
        qh[j * 4 + e] = p;
      }
#else
#pragma unroll
      for (int e = 0; e < 8; ++e) qf[j * 8 + e] = b2f(qq[e]) * 0.125f;
#endif
    }
  }
  __syncthreads();  // staging complete (the only barrier)
  if (q >= len) return;  // pair threads exit together (same q)

  f32x4 acc[16];
#pragma unroll
  for (int dq = 0; dq < 16; ++dq) acc[dq] = (f32x4){0.f, 0.f, 0.f, 0.f};
  float m = -INFINITY, sum = 0.f;

  for (int s = ks; s < len; s += 2) {
    float a0 = 0.f, a1 = 0.f, a2 = 0.f, a3 = 0.f;
#if USE_FDOT2
#pragma unroll
    for (int j = 0; j < 8; ++j) {
      f16x8 kk = __builtin_bit_cast(f16x8, *(const u16x8*)&Ksb[s * 64 + j * 8]);
      f16x2 k0 = {kk[0], kk[1]}, k1 = {kk[2], kk[3]};
      f16x2 k2 = {kk[4], kk[5]}, k3 = {kk[6], kk[7]};
      a0 = __builtin_amdgcn_fdot2(qh[j * 4 + 0], k0, a0, false);
      a1 = __builtin_amdgcn_fdot2(qh[j * 4 + 1], k1, a1, false);
      a2 = __builtin_amdgcn_fdot2(qh[j * 4 + 2], k2, a2, false);
      a3 = __builtin_amdgcn_fdot2(qh[j * 4 + 3], k3, a3, false);
    }
    float a = ((a0 + a1) + (a2 + a3)) * 0.125f;
#else
#pragma unroll
    for (int j = 0; j < 8; ++j) {
      u16x8 kk = *(const u16x8*)&Ksb[s * 64 + j * 8];  // broadcast
      a0 += qf[j * 8 + 0] * b2f(kk[0]);
      a1 += qf[j * 8 + 1] * b2f(kk[1]);
      a2 += qf[j * 8 + 2] * b2f(kk[2]);
      a3 += qf[j * 8 + 3] * b2f(kk[3]);
      a0 += qf[j * 8 + 4] * b2f(kk[4]);
      a1 += qf[j * 8 + 5] * b2f(kk[5]);
      a2 += qf[j * 8 + 6] * b2f(kk[6]);
      a3 += qf[j * 8 + 7] * b2f(kk[7]);
    }
    float a = (a0 + a1) + (a2 + a3);
#endif
    if (a > m + 8.f) {  // deferred rescale (T13)
      float cs = __expf(m - a);  // first key: exp(-inf - a) = 0 zeroes null state
      sum *= cs;
#pragma unroll
      for (int dq = 0; dq < 16; ++dq) acc[dq] *= cs;
      m = a;
    }
    float p = __expf(a - m);
    sum += p;
#pragma unroll
    for (int dq = 0; dq < 16; ++dq)
      acc[dq] += p * *(const f32x4*)&Vs[s * 64 + dq * 4];  // broadcast
  }

  // Pair merge — convergent shfls; both lanes of the pair are active here.
  float m2 = __shfl_xor(m, 1);
  float sum2 = __shfl_xor(sum, 1);
  float newm = fmaxf(m, m2);
  float cs = __expf(m - newm);    // ks=1 with no keys: exp(-inf - finite) = 0
  float cs2 = __expf(m2 - newm);
  float inv = 1.f / (sum * cs + sum2 * cs2);
  u16* op = out + (size_t)(ob + q) * ND + h * 64 + ks * 32;
#pragma unroll
  for (int i = 0; i < 8; ++i) {
    f32x4 mine = (ks == 0) ? acc[i] : acc[8 + i];      // my write-half dq
    f32x4 send = (ks == 0) ? acc[8 + i] : acc[i];      // partner's write-half dq
    f32x4 recv;
#pragma unroll
    for (int e = 0; e < 4; ++e) recv[e] = __shfl_xor(send[e], 1);
    u16x4 o;
#pragma unroll
    for (int e = 0; e < 4; ++e)
      o[e] = f2b((mine[e] * cs + recv[e] * cs2) * inv);
    *(u16x4*)(op + i * 4) = o;
  }
}

// ---------------------------------------------------------------------------
// x = LN(in) * g + b ; VARLEN: rows >= *pMr exit (uniform, pre-barrier).
// ---------------------------------------------------------------------------
__global__ __launch_bounds__(128) void add_ln_kernel(const float* __restrict__ in,
                                                     float* __restrict__ x,
                                                     u16* __restrict__ xb,
                                                     const float* __restrict__ g,
                                                     const float* __restrict__ bb,
                                                     const int* __restrict__ pMr) {
  const int row = blockIdx.x;
  if (row >= *pMr) return;
  const int t = threadIdx.x;
  const size_t base = (size_t)row * ND + t * 4;
  float4 v = *(const float4*)(in + base);
  float s = (v.x + v.y) + (v.z + v.w);
  float q = (v.x * v.x + v.y * v.y) + (v.z * v.z + v.w * v.w);
#pragma unroll
  for (int off = 32; off; off >>= 1) {
    s += __shfl_down(s, off);
    q += __shfl_down(q, off);
  }
  __shared__ float sb[4];
  const int wid = t >> 6;
  if ((t & 63) == 0) { sb[wid * 2] = s; sb[wid * 2 + 1] = q; }
  __syncthreads();
  float ts = sb[0] + sb[2];
  float tq = sb[1] + sb[3];
  float mean = ts * (1.f / (float)ND);
  float var = tq * (1.f / (float)ND) - mean * mean;
  float rstd = rsqrtf(var + 1e-5f);
  float4 gg = *(const float4*)(g + t * 4);
  float4 bv = *(const float4*)(bb + t * 4);
  float o0 = (v.x - mean) * rstd * gg.x + bv.x;
  float o1 = (v.y - mean) * rstd * gg.y + bv.y;
  float o2 = (v.z - mean) * rstd * gg.z + bv.z;
  float o3 = (v.w - mean) * rstd * gg.w + bv.w;
  *(float4*)(x + base) = (float4){o0, o1, o2, o3};
  u16x4 ob = {f2b(o0), f2b(o1), f2b(o2), f2b(o3)};
  *(u16x4*)(xb + base) = ob;
}

// ---------------------------------------------------------------------------
// w2sum[d] = sum_o attn_w[o, D + d]   (s_q and attn_b cancel in the softmax)
// ---------------------------------------------------------------------------
__global__ __launch_bounds__(64) void w2sum_kernel(const float* __restrict__ attn_w,
                                                   float* __restrict__ w2sum) {
  int d = blockIdx.x * 64 + threadIdx.x;
  float s = 0.f;
  for (int o = 0; o < ND; ++o) s += attn_w[(size_t)o * 1024 + 512 + d];
  w2sum[d] = s;
}

// ---------------------------------------------------------------------------
// VARLEN pooling head, race-free (round-8 proven): write-once sv, shfl
// reductions into red[], exp'd weights in separate pv[].
// ---------------------------------------------------------------------------
__global__ __launch_bounds__(256) void pool_kernel(const float* __restrict__ x,
                                                   const int* __restrict__ offs,
                                                   int BC,
                                                   const float* __restrict__ w2sum,
                                                   float* __restrict__ out) {
  const int b = blockIdx.x;
  const int c = b / BC;
  const int ob = offs[b] - offs[c * BC];
  const int len = offs[b + 1] - offs[b];  // >= 1
  const float* xr0 = x + ((size_t)c * BC * NS + ob) * ND;
  const int t = threadIdx.x;
  __shared__ float wsm[ND];
  __shared__ float sv[NS + 12];
  __shared__ float pv[256];
  __shared__ float red[8];
  wsm[t] = w2sum[t];
  wsm[t + 256] = w2sum[t + 256];
  __syncthreads();
  const int wv = t >> 6, ln = t & 63;
  for (int s = wv; s < len; s += 4) {
    const float* xr = xr0 + (size_t)s * ND;
    float acc = 0.f;
#pragma unroll
    for (int j = 0; j < 8; ++j) acc += xr[ln + j * 64] * wsm[ln + j * 64];
#pragma unroll
    for (int off = 32; off; off >>= 1) acc += __shfl_xor(acc, off);
    if (ln == 0) sv[s] = acc;
  }
  __syncthreads();
  float v = (t < len) ? sv[t] : -INFINITY;
  float m_ = v;
#pragma unroll
  for (int off = 32; off; off >>= 1) m_ = fmaxf(m_, __shfl_xor(m_, off));
  if (ln == 0) red[wv] = m_;
  __syncthreads();
  const float mx = fmaxf(fmaxf(red[0], red[1]), fmaxf(red[2], red[3]));
  float e = (t < len) ? __expf(v - mx) : 0.f;
  pv[t] = e;
  float s_ = e;
#pragma unroll
  for (int off = 32; off; off >>= 1) s_ += __shfl_xor(s_, off);
  if (ln == 0) red[4 + wv] = s_;
  __syncthreads();
  const float inv = 1.f / ((red[4] + red[5]) + (red[6] + red[7]));
  float a0 = 0.f, a1 = 0.f;
  for (int s = 0; s < len; ++s) {
    float p = pv[s];
    const float* xr = xr0 + (size_t)s * ND;
    a0 += p * xr[t];
    a1 += p * xr[t + 256];
  }
  out[(size_t)b * ND + t] = a0 * inv;
  out[(size_t)b * ND + t + 256] = a1 * inv;
}

// ---------------------------------------------------------------------------
extern "C" void kernel_launch(void* const* d_in, const int* in_sizes, int n_in,
                              void* d_out, int out_size, void* d_ws, size_t ws_size,
                              hipStream_t stream) {
  const int* mask = (const int*)d_in[0];
  const float* emb = (const float*)d_in[1];
  const float* in_proj_w = (const float*)d_in[2];
  const float* in_proj_b = (const float*)d_in[3];
  const float* out_proj_w = (const float*)d_in[4];
  const float* out_proj_b = (const float*)d_in[5];
  const float* lin1_w = (const float*)d_in[6];
  const float* lin1_b = (const float*)d_in[7];
  const float* lin2_w = (const float*)d_in[8];
  const float* lin2_b = (const float*)d_in[9];
  const float* ln1_w = (const float*)d_in[10];
  const float* ln1_b = (const float*)d_in[11];
  const float* ln2_w = (const float*)d_in[12];
  const float* ln2_b = (const float*)d_in[13];
  const float* attn_w = (const float*)d_in[14];
  // d_in[15] = attn_b: constant over softmax axis -> cancels; unused.

  char* wsb = (char*)d_ws;
  size_t off = 0;
  auto alloc = [&](size_t bytes) -> char* {
    char* p = wsb + off;
    off += (bytes + 255) & ~(size_t)255;
    return p;
  };
  float* x   = (float*)alloc((size_t)NM * ND * 4);   // compacted, chunk-strided
  u16* xb    = (u16*)alloc((size_t)NM * ND * 2);     // compacted bf16 mirror
  u16* wqkv  = (u16*)alloc((size_t)NL * 1536 * 512 * 2);
  u16* wout  = (u16*)alloc((size_t)NL * 512 * 512 * 2);
  u16* w1b   = (u16*)alloc((size_t)NL * 2048 * 512 * 2);
  u16* w2b   = (u16*)alloc((size_t)NL * 512 * 2048 * 2);
  float* w2s = (float*)alloc(ND * 4);
  int* offs  = (int*)alloc((NB + 1) * 4);
  int* meta  = (int*)alloc(16 * 4);   // Mr per chunk (<= 8 chunks)
  size_t fixedEnd = off;

  int BC = 32;
  const int cands[4] = {256, 128, 64, 32};
  auto alup = [](size_t b) { return (b + 255) & ~(size_t)255; };
  for (int ci = 0; ci < 4; ++ci) {
    size_t Mc = (size_t)cands[ci] * NS;
    size_t need = fixedEnd + alup(Mc * 2048 * 2) + alup(Mc * 512 * 2) + alup(Mc * 512 * 4);
    if (need <= ws_size) { BC = cands[ci]; break; }
  }
  const size_t Mc = (size_t)BC * NS;
  const int NC = NB / BC;
  u16* big    = (u16*)alloc(Mc * 2048 * 2);
  u16* bufA   = (u16*)alloc(Mc * 512 * 2);
  float* bufT = (float*)alloc(Mc * 512 * 4);

  cast_kernel<<<NL * 1536 * 512 / 1024, 256, 0, stream>>>(in_proj_w, wqkv);
  cast_kernel<<<NL * 512 * 512 / 1024, 256, 0, stream>>>(out_proj_w, wout);
  cast_kernel<<<NL * 2048 * 512 / 1024, 256, 0, stream>>>(lin1_w, w1b);
  cast_kernel<<<NL * 512 * 2048 / 1024, 256, 0, stream>>>(lin2_w, w2b);
  scan_kernel<<<1, 256, 0, stream>>>(mask, offs, meta, BC, NC);
  pe_compact_kernel<<<NM, 128, 0, stream>>>(emb, offs, BC, x, xb);

  for (int i = 0; i < NL; ++i) {
    for (int c = 0; c < NC; ++c) {
      float* xc = x + (size_t)c * Mc * ND;
      u16* xbc = xb + (size_t)c * Mc * ND;
      const int* pMr = meta + c;
      gemm_mfma<128, false, true, false><<<dim3(1536 / 128, Mc / 128), 256, 0, stream>>>(
          xbc, wqkv + (size_t)i * 1536 * 512, in_proj_b + i * 1536, nullptr, nullptr, big, pMr, 1536, 512);
      attn_kernel<<<BC * NH, 256, 0, stream>>>(big, offs, c * BC, bufA);
      gemm_mfma<64, false, false, true><<<dim3(512 / 128, Mc / 64), 256, 0, stream>>>(
          bufA, wout + (size_t)i * 512 * 512, out_proj_b + i * 512, xc, bufT, nullptr, pMr, 512, 512);
      add_ln_kernel<<<Mc, 128, 0, stream>>>(bufT, xc, xbc, ln1_w + i * 512, ln1_b + i * 512, pMr);
      gemm_mfma<128, true, true, false><<<dim3(2048 / 128, Mc / 128), 256, 0, stream>>>(
          xbc, w1b + (size_t)i * 2048 * 512, lin1_b + i * 2048, nullptr, nullptr, big, pMr, 2048, 512);
      gemm_mfma<64, false, false, true><<<dim3(512 / 128, Mc / 64), 256, 0, stream>>>(
          big, w2b + (size_t)i * 512 * 2048, lin2_b + i * 512, xc, bufT, nullptr, pMr, 512, 2048);
      add_ln_kernel<<<Mc, 128, 0, stream>>>(bufT, xc, xbc, ln2_w + i * 512, ln2_b + i * 512, pMr);
    }
  }

  w2sum_kernel<<<ND / 64, 64, 0, stream>>>(attn_w, w2s);
  pool_kernel<<<NB, 256, 0, stream>>>(x, offs, BC, w2s, (float*)d_out);
}